// Round 14
// baseline (195.410 us; speedup 1.0000x reference)
//
#include <hip/hip_runtime.h>

// Masked self-attention, B=4 T=2048 C=1024 (single head, head dim = C).
// Round-13 pipeline (best: 183.9 µs) + reduce fused into out-proj:
//  gemm8  : 256x256 / BK=64 / 8-wave 8-barrier pipelined, vmcnt(4)/K-tile.
//           EPI 3 = bf16+bias[col] (QK), 5 = split-K2 partial (PV),
//           6 = scores exp+rowsum (tri early-exit).
//  gemm2ph: 256x128 2-phase (Vt-proj bf16+bias[row]).
//  gemm2f : 256x128 2-phase out-proj with A = (P0+P1)/rowsum computed in
//           reg-staging (T14: loads early, swizzled ds_write late) — the
//           separate reduce pass is eliminated.
// LDS swizzle: 16B-slot ^= (row&7), both-sides. T1 XCD-bijective swizzle.
// Pipeline: prep | QK | Vt | scores | PV splitK2 | out(fused reduce).

typedef __attribute__((ext_vector_type(8))) short short8;
typedef __attribute__((ext_vector_type(4))) float f32x4;
typedef __attribute__((ext_vector_type(4))) unsigned short us4;
typedef __attribute__((ext_vector_type(8))) unsigned short us8;
typedef __attribute__((ext_vector_type(4))) float fl4;

__device__ __forceinline__ unsigned short f2b(float f) {
  unsigned int u = __builtin_bit_cast(unsigned int, f);
  u += 0x7fffu + ((u >> 16) & 1u);   // round-to-nearest-even
  return (unsigned short)(u >> 16);
}
__device__ __forceinline__ float b2f(unsigned short h) {
  unsigned int u = ((unsigned int)h) << 16;
  return __builtin_bit_cast(float, u);
}

// ---------------- merged prep: converts + bias packing + rowsum zero -------
__global__ __launch_bounds__(256) void prep_kernel(
    const float* __restrict__ x,
    const float* __restrict__ Wq, const float* __restrict__ Wk,
    const float* __restrict__ Wv, const float* __restrict__ Wo,
    const float* __restrict__ bq, const float* __restrict__ bk,
    const float* __restrict__ bv, const float* __restrict__ bo,
    unsigned short* __restrict__ xb, unsigned short* __restrict__ Wqkvb,
    unsigned short* __restrict__ Wob, float* __restrict__ bws,
    float* __restrict__ rows) {
  const int bid = blockIdx.x;
  if (bid < 8192) {
    const int i = bid * 256 + threadIdx.x;
    fl4 f = *(const fl4*)&x[(size_t)i << 2];
    us4 o;
#pragma unroll
    for (int j = 0; j < 4; ++j) o[j] = f2b(f[j]);
    *(us4*)&xb[(size_t)i << 2] = o;
  } else if (bid < 12288) {
    const int w = (bid - 8192) >> 10;
    const int i = ((bid - 8192) & 1023) * 256 + threadIdx.x;
    const float* s = w == 0 ? Wq : w == 1 ? Wk : w == 2 ? Wv : Wo;
    unsigned short* d = w < 3 ? Wqkvb + (size_t)w * 1024 * 1024 : Wob;
    fl4 f = *(const fl4*)&s[(size_t)i << 2];
    us4 o;
#pragma unroll
    for (int j = 0; j < 4; ++j) o[j] = f2b(f[j]);
    *(us4*)&d[(size_t)i << 2] = o;
  } else if (bid < 12304) {
    const int i = (bid - 12288) * 256 + threadIdx.x;
    const int sel = i >> 10, idx = i & 1023;
    const float* p = sel == 0 ? bq : sel == 1 ? bk : sel == 2 ? bv : bo;
    bws[i] = p[idx];
  } else {
    for (int k = threadIdx.x; k < 8192; k += 256) rows[k] = 0.f;
  }
}

#define RD_A(dst, basep)                                                   \
  _Pragma("unroll") for (int mi = 0; mi < 4; ++mi)                         \
  _Pragma("unroll") for (int ks = 0; ks < 2; ++ks)                         \
      dst[mi][ks] = *(const short8*)((basep) + offA[mi][ks]);

#define RD_B(dst, basep)                                                   \
  _Pragma("unroll") for (int nj = 0; nj < 2; ++nj)                         \
  _Pragma("unroll") for (int ks = 0; ks < 2; ++ks)                         \
      dst[nj][ks] = *(const short8*)((basep) + offB[nj][ks]);

#define MFMA16(AF, BF, MI0, NJ0)                                           \
  __builtin_amdgcn_s_setprio(1);                                           \
  _Pragma("unroll") for (int ks = 0; ks < 2; ++ks)                         \
  _Pragma("unroll") for (int mi = 0; mi < 4; ++mi)                         \
  _Pragma("unroll") for (int nj = 0; nj < 2; ++nj)                         \
      acc[(MI0) + mi][(NJ0) + nj] = __builtin_amdgcn_mfma_f32_16x16x32_bf16( \
          AF[mi][ks], BF[nj][ks], acc[(MI0) + mi][(NJ0) + nj], 0, 0, 0);   \
  __builtin_amdgcn_s_setprio(0);

// 8-barrier pipelined K-loop (template barrier discipline).
#define KLOOP_BODY                                                         \
  stA(0, 0, 0); stB(0, 0, 0); stA(0, 1, 0); stB(0, 1, 0);                  \
  stB(1, 0, 1); stA(1, 1, 1);                                              \
  asm volatile("s_waitcnt vmcnt(4)" ::: "memory");                         \
  __builtin_amdgcn_s_barrier();                                            \
  for (int t = 0; t < nt; ++t) {                                           \
    const int buf = t & 1, nbuf = buf ^ 1;                                 \
    const char* Ab0 = (const char*)&lA[buf][0][0];                         \
    const char* Ab1 = (const char*)&lA[buf][1][0];                         \
    const char* Bb0 = (const char*)&lB[buf][0][0];                         \
    const char* Bb1 = (const char*)&lB[buf][1][0];                         \
    short8 a0[4][2], a1[4][2], b0[2][2], b1[2][2];                         \
    RD_A(a0, Ab0);                                                         \
    RD_B(b0, Bb0);                                                         \
    stB(nbuf, 1, t + 1);                                                   \
    __builtin_amdgcn_s_barrier();                                          \
    RD_A(a1, Ab1);                                                         \
    MFMA16(a0, b0, 0, 0);                                                  \
    __builtin_amdgcn_s_barrier();                                          \
    stA(nbuf, 0, t + 1);                                                   \
    __builtin_amdgcn_s_barrier();                                          \
    RD_B(b1, Bb1);                                                         \
    MFMA16(a1, b0, 4, 0);                                                  \
    __builtin_amdgcn_s_barrier();                                          \
    stB(buf, 0, t + 2);                                                    \
    __builtin_amdgcn_s_barrier();                                          \
    MFMA16(a1, b1, 4, 2);                                                  \
    __builtin_amdgcn_s_barrier();                                          \
    stA(buf, 1, t + 2);                                                    \
    asm volatile("s_waitcnt vmcnt(4)" ::: "memory");                       \
    __builtin_amdgcn_s_barrier();                                          \
    MFMA16(a0, b1, 0, 2);                                                  \
    __builtin_amdgcn_s_barrier();                                          \
  }                                                                        \
  asm volatile("s_waitcnt vmcnt(0)" ::: "memory");

// ---------------- gemm8: 256x256 8-barrier pipelined ----------------
template<int EPI, bool SPLIT2, bool SKIP_UPPER>
__global__ __launch_bounds__(512, 2)
void gemm8(const unsigned short* __restrict__ A, const unsigned short* __restrict__ B,
           void* __restrict__ Cout, const float* __restrict__ bias,
           float* __restrict__ rows, float scale, int K,
           int lda, int ldb, int ldc,
           long long sAz, long long sBz, long long sCz)
{
  const int gx = gridDim.x;
  const int nwg = gx * gridDim.y;
  int flat = blockIdx.y * gx + blockIdx.x;
  { const int q = nwg >> 3, r = nwg & 7, xc = flat & 7, i = flat >> 3;
    flat = (xc < r ? xc * (q + 1) : r * (q + 1) + (xc - r) * q) + i; }
  const int m0 = (flat / gx) << 8;
  const int n0 = (flat % gx) << 8;
  if (SKIP_UPPER && n0 > m0 + 255) return;   // fully-masked score block
  const int zraw = blockIdx.z;
  const int z = SPLIT2 ? (zraw >> 1) : zraw;

  int kBeg = 0, kEnd = K;
  if (SPLIT2) {                        // balanced causal half (PV)
    const int kFull = m0 + 256;
    const int kMid = kFull >> 1;
    kBeg = (zraw & 1) ? kMid : 0;
    kEnd = (zraw & 1) ? kFull : kMid;
  }
  const int nt = (kEnd - kBeg) >> 6;

  __shared__ unsigned short lA[2][2][8192];
  __shared__ unsigned short lB[2][2][8192];

  const int tid = threadIdx.x, lane = tid & 63, wid = tid >> 6;
  const int wm = wid >> 2, wn = wid & 3;
  const int fr = lane & 15, kg = lane >> 4;

  const unsigned short* Ab = A + (size_t)z * sAz;
  const unsigned short* Bb = B + (size_t)z * sBz;

  const int xorv = (fr & 7) << 4;
  int offA[4][2], offB[2][2];
#pragma unroll
  for (int mi = 0; mi < 4; ++mi)
#pragma unroll
    for (int ks = 0; ks < 2; ++ks)
      offA[mi][ks] = ((wm << 6) + (mi << 4) + fr) * 128 + (((ks << 6) + (kg << 4)) ^ xorv);
#pragma unroll
  for (int nj = 0; nj < 2; ++nj)
#pragma unroll
    for (int ks = 0; ks < 2; ++ks)
      offB[nj][ks] = ((wn << 5) + (nj << 4) + fr) * 128 + (((ks << 6) + (kg << 4)) ^ xorv);

  const int srow = tid >> 3;
  const int scol = (((tid & 7) ^ (srow & 7)) << 3);
  const unsigned short* aS = Ab + (size_t)(m0 + srow) * lda + scol + kBeg;
  const unsigned short* bS = Bb + (size_t)(n0 + srow) * ldb + scol + kBeg;

  auto stA = [&](int buf, int h, int tt) {
    int ttc = tt < nt ? tt : nt - 1;
    const unsigned short* s0 = aS + (size_t)(h << 7) * lda + (ttc << 6);
#pragma unroll
    for (int c = 0; c < 2; ++c)
      __builtin_amdgcn_global_load_lds(
          (const __attribute__((address_space(1))) void*)(s0 + (size_t)(c << 6) * lda),
          (__attribute__((address_space(3))) void*)((char*)&lA[buf][h][0] + (c << 13) + (tid << 4)),
          16, 0, 0);
  };
  auto stB = [&](int buf, int h, int tt) {
    int ttc = tt < nt ? tt : nt - 1;
    const unsigned short* s0 = bS + (size_t)(h << 7) * ldb + (ttc << 6);
#pragma unroll
    for (int c = 0; c < 2; ++c)
      __builtin_amdgcn_global_load_lds(
          (const __attribute__((address_space(1))) void*)(s0 + (size_t)(c << 6) * ldb),
          (__attribute__((address_space(3))) void*)((char*)&lB[buf][h][0] + (c << 13) + (tid << 4)),
          16, 0, 0);
  };

  f32x4 acc[8][4];
#pragma unroll
  for (int i = 0; i < 8; ++i)
#pragma unroll
    for (int j = 0; j < 4; ++j) acc[i][j] = f32x4{0.f, 0.f, 0.f, 0.f};

  KLOOP_BODY

  if (EPI == 6) {
    unsigned short* Ch = (unsigned short*)Cout + (size_t)z * sCz;
#pragma unroll
    for (int mig = 0; mig < 8; ++mig) {
      const int row = m0 + (mig >> 2) * 128 + wm * 64 + (mig & 3) * 16 + (kg << 2);
#pragma unroll
      for (int jj = 0; jj < 4; ++jj) {
        const int r = row + jj;
        float rs = 0.f;
#pragma unroll
        for (int njg = 0; njg < 4; ++njg) {
          const int col = n0 + (njg >> 1) * 128 + wn * 32 + (njg & 1) * 16 + fr;
          const float ee = (col <= r) ? __expf(acc[mig][njg][jj] * scale) : 0.f;
          rs += ee;
          Ch[(size_t)r * ldc + col] = f2b(ee);
        }
#pragma unroll
        for (int mk = 1; mk <= 8; mk <<= 1) rs += __shfl_xor(rs, mk, 64);
        if (fr == 0) atomicAdd(&rows[z * 2048 + r], rs);
      }
    }
    return;
  }
#pragma unroll
  for (int mig = 0; mig < 8; ++mig)
#pragma unroll
    for (int njg = 0; njg < 4; ++njg) {
      const int row = m0 + (mig >> 2) * 128 + wm * 64 + (mig & 3) * 16 + (kg << 2);
      const int col = n0 + (njg >> 1) * 128 + wn * 32 + (njg & 1) * 16 + fr;
      f32x4 v = acc[mig][njg];
      if (EPI == 3) {
        unsigned short* Ch = (unsigned short*)Cout;
        const float bb = bias[col];
#pragma unroll
        for (int jj = 0; jj < 4; ++jj)
          Ch[(size_t)(row + jj) * ldc + col] = f2b(v[jj] + bb);
      } else {   // EPI == 5: split-K2 partial; half selects P0|P1
        unsigned short* Ch = (unsigned short*)Cout +
            (size_t)(zraw & 1) * 8388608 + (size_t)z * sCz;
#pragma unroll
        for (int jj = 0; jj < 4; ++jj)
          Ch[(size_t)(row + jj) * ldc + col] = f2b(v[jj]);
      }
    }
}

// ---------------- gemm2ph: 256x128 2-phase (Vt-proj, bf16+bias[row]) -------
__global__ __launch_bounds__(512, 2)
void gemm2ph(const unsigned short* __restrict__ A, const unsigned short* __restrict__ B,
             unsigned short* __restrict__ Cout, const float* __restrict__ bias,
             int K, int lda, int ldb, int ldc)
{
  const int gx = gridDim.x;
  const int nwg = gx * gridDim.y;
  int flat = blockIdx.y * gx + blockIdx.x;
  { const int q = nwg >> 3, r = nwg & 7, xc = flat & 7, i = flat >> 3;
    flat = (xc < r ? xc * (q + 1) : r * (q + 1) + (xc - r) * q) + i; }
  const int m0 = (flat / gx) << 8;
  const int n0 = (flat % gx) << 7;
  const int nt = K >> 6;

  __shared__ unsigned short lA[2][2][8192];   // 64 KB
  __shared__ unsigned short lB[2][8192];      // 32 KB

  const int tid = threadIdx.x, lane = tid & 63, wid = tid >> 6;
  const int wm = wid >> 2, wn = wid & 3;
  const int fr = lane & 15, kg = lane >> 4;

  const int xorv = (fr & 7) << 4;
  int offA[4][2], offB[2][2];
#pragma unroll
  for (int mi = 0; mi < 4; ++mi)
#pragma unroll
    for (int ks = 0; ks < 2; ++ks)
      offA[mi][ks] = ((wm << 6) + (mi << 4) + fr) * 128 + (((ks << 6) + (kg << 4)) ^ xorv);
#pragma unroll
  for (int nj = 0; nj < 2; ++nj)
#pragma unroll
    for (int ks = 0; ks < 2; ++ks)
      offB[nj][ks] = ((wn << 5) + (nj << 4) + fr) * 128 + (((ks << 6) + (kg << 4)) ^ xorv);

  const int srow = tid >> 3;
  const int scol = (((tid & 7) ^ (srow & 7)) << 3);
  const unsigned short* aS = A + (size_t)(m0 + srow) * lda + scol;
  const unsigned short* bS = B + (size_t)(n0 + srow) * ldb + scol;

  auto stA = [&](int buf, int h, int tt) {
    int ttc = tt < nt ? tt : nt - 1;
    const unsigned short* s0 = aS + (size_t)(h << 7) * lda + (ttc << 6);
#pragma unroll
    for (int c = 0; c < 2; ++c)
      __builtin_amdgcn_global_load_lds(
          (const __attribute__((address_space(1))) void*)(s0 + (size_t)(c << 6) * lda),
          (__attribute__((address_space(3))) void*)((char*)&lA[buf][h][0] + (c << 13) + (tid << 4)),
          16, 0, 0);
  };
  auto stB = [&](int buf, int tt) {
    int ttc = tt < nt ? tt : nt - 1;
    const unsigned short* s0 = bS + (ttc << 6);
#pragma unroll
    for (int c = 0; c < 2; ++c)
      __builtin_amdgcn_global_load_lds(
          (const __attribute__((address_space(1))) void*)(s0 + (size_t)(c << 6) * ldb),
          (__attribute__((address_space(3))) void*)((char*)&lB[buf][0] + (c << 13) + (tid << 4)),
          16, 0, 0);
  };

  f32x4 acc[8][2];
#pragma unroll
  for (int i = 0; i < 8; ++i)
#pragma unroll
    for (int j = 0; j < 2; ++j) acc[i][j] = f32x4{0.f, 0.f, 0.f, 0.f};

  stB(0, 0); stA(0, 0, 0); stA(0, 1, 0);
  asm volatile("s_waitcnt vmcnt(2)" ::: "memory");
  __builtin_amdgcn_s_barrier();

  for (int t = 0; t < nt; ++t) {
    const int buf = t & 1, nbuf = buf ^ 1;
    const char* Ab0 = (const char*)&lA[buf][0][0];
    const char* Ab1 = (const char*)&lA[buf][1][0];
    const char* Bbp = (const char*)&lB[buf][0];

    short8 a0[4][2], a1[4][2], b0[2][2];

    RD_A(a0, Ab0);
    RD_B(b0, Bbp);
    stB(nbuf, t + 1); stA(nbuf, 0, t + 1);
    asm volatile("s_waitcnt vmcnt(4)" ::: "memory");
    __builtin_amdgcn_s_barrier();
    MFMA16(a0, b0, 0, 0);
    __builtin_amdgcn_s_barrier();

    RD_A(a1, Ab1);
    stA(nbuf, 1, t + 1);
    asm volatile("s_waitcnt vmcnt(2)" ::: "memory");
    __builtin_amdgcn_s_barrier();
    MFMA16(a1, b0, 4, 0);
    __builtin_amdgcn_s_barrier();
  }
  asm volatile("s_waitcnt vmcnt(0)" ::: "memory");

#pragma unroll
  for (int mig = 0; mig < 8; ++mig)
#pragma unroll
    for (int njg = 0; njg < 2; ++njg) {
      const int row = m0 + (mig >> 2) * 128 + wm * 64 + (mig & 3) * 16 + (kg << 2);
      const int col = n0 + wn * 32 + njg * 16 + fr;
      f32x4 v = acc[mig][njg];
#pragma unroll
      for (int jj = 0; jj < 4; ++jj)
        Cout[(size_t)(row + jj) * ldc + col] = f2b(v[jj] + bias[row + jj]);
    }
}

// ---- gemm2f: out-proj with fused reduce: A = (P0+P1)/rowsum (reg-staged) --
__global__ __launch_bounds__(512, 2)
void gemm2f(const unsigned short* __restrict__ P0b,
            const unsigned short* __restrict__ P1b,
            const unsigned short* __restrict__ B,
            float* __restrict__ Cout, const float* __restrict__ bias,
            const float* __restrict__ rows,
            int K, int lda, int ldb, int ldc)
{
  const int gx = gridDim.x;
  const int nwg = gx * gridDim.y;
  int flat = blockIdx.y * gx + blockIdx.x;
  { const int q = nwg >> 3, r = nwg & 7, xc = flat & 7, i = flat >> 3;
    flat = (xc < r ? xc * (q + 1) : r * (q + 1) + (xc - r) * q) + i; }
  const int m0 = (flat / gx) << 8;
  const int n0 = (flat % gx) << 7;
  const int nt = K >> 6;

  __shared__ unsigned short lA[2][2][8192];   // 64 KB
  __shared__ unsigned short lB[2][8192];      // 32 KB

  const int tid = threadIdx.x, lane = tid & 63, wid = tid >> 6;
  const int wm = wid >> 2, wn = wid & 3;
  const int fr = lane & 15, kg = lane >> 4;

  const int xorv = (fr & 7) << 4;
  int offA[4][2], offB[2][2];
#pragma unroll
  for (int mi = 0; mi < 4; ++mi)
#pragma unroll
    for (int ks = 0; ks < 2; ++ks)
      offA[mi][ks] = ((wm << 6) + (mi << 4) + fr) * 128 + (((ks << 6) + (kg << 4)) ^ xorv);
#pragma unroll
  for (int nj = 0; nj < 2; ++nj)
#pragma unroll
    for (int ks = 0; ks < 2; ++ks)
      offB[nj][ks] = ((wn << 5) + (nj << 4) + fr) * 128 + (((ks << 6) + (kg << 4)) ^ xorv);

  const int srow = tid >> 3;
  const int scolS = (((tid & 7) ^ (srow & 7)) << 3);  // B source (swizzled)
  const int scolL = (tid & 7) << 3;                   // A source (linear)
  const unsigned short* bS = B + (size_t)(n0 + srow) * ldb + scolS;

  // A per (h,c): global rows are tile-invariant -> hoist ptrs, inv, dest offs
  const unsigned short* pA0[2][2];
  const unsigned short* pA1[2][2];
  float inv[2][2];
  int dOff[2][2];
#pragma unroll
  for (int h = 0; h < 2; ++h)
#pragma unroll
    for (int c = 0; c < 2; ++c) {
      const int r = m0 + h * 128 + c * 64 + srow;
      pA0[h][c] = P0b + (size_t)r * lda + scolL;
      pA1[h][c] = P1b + (size_t)r * lda + scolL;
      inv[h][c] = 1.f / rows[r];
      // dest: row (c*64+srow) of half h, slot (tid&7)^(row&7); (row&7)==(srow&7)
      dOff[h][c] = (c * 64 + srow) * 128 + (((tid & 7) ^ (srow & 7)) << 4);
    }

  auto stB = [&](int buf, int tt) {
    int ttc = tt < nt ? tt : nt - 1;
    const unsigned short* s0 = bS + (ttc << 6);
#pragma unroll
    for (int c = 0; c < 2; ++c)
      __builtin_amdgcn_global_load_lds(
          (const __attribute__((address_space(1))) void*)(s0 + (size_t)(c << 6) * ldb),
          (__attribute__((address_space(3))) void*)((char*)&lB[buf][0] + (c << 13) + (tid << 4)),
          16, 0, 0);
  };

  us8 r0[2][2], r1[2][2];
  auto ldA = [&](int tt) {                 // 8 global_load_dwordx4 -> regs
    int ttc = tt < nt ? tt : nt - 1;
#pragma unroll
    for (int h = 0; h < 2; ++h)
#pragma unroll
      for (int c = 0; c < 2; ++c) {
        r0[h][c] = *(const us8*)(pA0[h][c] + (ttc << 6));
        r1[h][c] = *(const us8*)(pA1[h][c] + (ttc << 6));
      }
  };
  auto wrA = [&](int buf) {                // add+scale+cvt, 4 swizzled writes
#pragma unroll
    for (int h = 0; h < 2; ++h)
#pragma unroll
      for (int c = 0; c < 2; ++c) {
        us8 o;
#pragma unroll
        for (int j = 0; j < 8; ++j)
          o[j] = f2b((b2f(r0[h][c][j]) + b2f(r1[h][c][j])) * inv[h][c]);
        *(us8*)((char*)&lA[buf][h][0] + dOff[h][c]) = o;
      }
  };

  f32x4 acc[8][2];
#pragma unroll
  for (int i = 0; i < 8; ++i)
#pragma unroll
    for (int j = 0; j < 2; ++j) acc[i][j] = f32x4{0.f, 0.f, 0.f, 0.f};

  // prologue: tile0 A via regs, B via gll; full drain once
  ldA(0);
  stB(0, 0);
  wrA(0);
  asm volatile("s_waitcnt vmcnt(0) lgkmcnt(0)" ::: "memory");
  __builtin_amdgcn_sched_barrier(0);
  __builtin_amdgcn_s_barrier();

  for (int t = 0; t < nt; ++t) {
    const int buf = t & 1, nbuf = buf ^ 1;
    const char* Ab0 = (const char*)&lA[buf][0][0];
    const char* Ab1 = (const char*)&lA[buf][1][0];
    const char* Bbp = (const char*)&lB[buf][0];

    short8 a0[4][2], a1[4][2], b0[2][2];

    // q0: issue t+1 A-loads (latency hides under RD+MFMA); stage B t+1
    ldA(t + 1);
    stB(nbuf, t + 1);
    RD_A(a0, Ab0);
    RD_B(b0, Bbp);
    __builtin_amdgcn_s_barrier();
    MFMA16(a0, b0, 0, 0);
    __builtin_amdgcn_s_barrier();

    // q1: write t+1 A into nbuf (compiler waits the loads); drain B + writes
    RD_A(a1, Ab1);
    wrA(nbuf);
    MFMA16(a1, b0, 4, 0);
    asm volatile("s_waitcnt vmcnt(0) lgkmcnt(0)" ::: "memory");
    __builtin_amdgcn_sched_barrier(0);
    __builtin_amdgcn_s_barrier();
  }

#pragma unroll
  for (int mig = 0; mig < 8; ++mig)
#pragma unroll
    for (int njg = 0; njg < 2; ++njg) {
      const int row = m0 + (mig >> 2) * 128 + wm * 64 + (mig & 3) * 16 + (kg << 2);
      const int col = n0 + wn * 32 + njg * 16 + fr;
      f32x4 v = acc[mig][njg];
      const float bb = bias[col];
#pragma unroll
      for (int jj = 0; jj < 4; ++jj)
        Cout[(size_t)(row + jj) * ldc + col] = v[jj] + bb;
    }
}

// ---------------- host-side launch ----------------
extern "C" void kernel_launch(void* const* d_in, const int* in_sizes, int n_in,
                              void* d_out, int out_size, void* d_ws, size_t ws_size,
                              hipStream_t stream) {
  (void)in_sizes; (void)n_in; (void)out_size; (void)ws_size;
  const float* x  = (const float*)d_in[0];
  const float* Wq = (const float*)d_in[1];
  const float* bq = (const float*)d_in[2];
  const float* Wk = (const float*)d_in[3];
  const float* bk = (const float*)d_in[4];
  const float* Wv = (const float*)d_in[5];
  const float* bv = (const float*)d_in[6];
  const float* Wo = (const float*)d_in[7];
  const float* bo = (const float*)d_in[8];

  const int B = 4, T = 2048, C = 1024;
  const int M = B * T;                                   // 8192

  unsigned short* xb    = (unsigned short*)d_ws;         // M*C
  unsigned short* Wqkvb = xb    + (size_t)M * C;         // [Wq|Wk|Wv]
  unsigned short* Wob   = Wqkvb + (size_t)3 * C * C;
  unsigned short* QK    = Wob   + (size_t)C * C;         // M*2C [Q|K]; later P0|P1
  unsigned short* Vt    = QK    + (size_t)M * 2 * C;     // [1024][8192]
  unsigned short* S     = Vt    + (size_t)M * C;         // B*T*T e-values
  float*          bws   = (float*)(S + (size_t)B * T * T);
  float*          rowsum= bws + 4096;                    // 8192 f32
  unsigned short* P0    = QK;
  unsigned short* P1    = QK + (size_t)M * C;

  // 1. prep
  prep_kernel<<<12305, 256, 0, stream>>>(x, Wq, Wk, Wv, Wo, bq, bk, bv, bo,
                                         xb, Wqkvb, Wob, bws, rowsum);

  // 2. QK projection (256 blocks)
  gemm8<3, false, false><<<dim3(2 * C / 256, M / 256, 1), 512, 0, stream>>>(
      xb, Wqkvb, QK, bws, nullptr, 1.f, C, C, C, 2 * C, 0LL, 0LL, 0LL);

  // 3. Vt = Wv @ x^T + bv[row] (256 blocks, BN=128)
  gemm2ph<<<dim3(M / 128, C / 256, 1), 512, 0, stream>>>(
      Wqkvb + (size_t)2 * C * C, xb, Vt, bws + 2 * C, C, C, C, M);

  // 4. scores: S = exp(Q K^T / 32) causal-masked + rowsum atomics
  gemm8<6, false, true><<<dim3(T / 256, T / 256, B), 512, 0, stream>>>(
      QK, QK + C, S, nullptr, rowsum, 0.03125f, C, 2 * C, 2 * C, T,
      (long long)T * 2 * C, (long long)T * 2 * C, (long long)T * T);

  // 5. PV split-K2: partials P0|P1 (z = batch*2 + half), 256 blocks
  gemm8<5, true, false><<<dim3(C / 256, T / 256, 2 * B), 512, 0, stream>>>(
      S, Vt, P0, nullptr, nullptr, 1.f, T, T, M, C,
      (long long)T * T, 2048LL, (long long)T * C);

  // 6. out = ((P0+P1)/rowsum) @ Wo^T + bo  (fused reduce, f32 out)
  gemm2f<<<dim3(C / 128, M / 256, 1), 512, 0, stream>>>(
      P0, P1, Wob, (float*)d_out, bws + 3 * C, rowsum, C, C, C, C);
}

// Round 15
// 189.789 us; speedup vs baseline: 1.0296x; 1.0296x over previous
//
#include <hip/hip_runtime.h>

// Masked self-attention, B=4 T=2048 C=1024 (single head, head dim = C).
// ALL GEMMs on the measured-fastest engine (r13 gemm2ph): 256x128 / BK=64 /
// 8-wave 2-phase pipelined, counted vmcnt(4)/(2) per phase (never 0 in-loop),
// 96 KB LDS, slot-XOR swizzle both-sides, XCD-bijective block swizzle.
//  EPI 3 = QK-proj  (bf16 + bias[col], 512 blocks, 2 rounds)
//  EPI 4 = Vt-proj  (bf16 + bias[row], 256 blocks)
//  EPI 6 = scores   (exp(v/32) causal-masked + rowsum atomics, 288 tri blocks)
//  EPI 7 = PV direct (causal kEnd, bf16 * 1/rowsum[row], 256 blocks) — no
//          split-K partials, no reduce pass.
//  EPI 2 = out-proj (f32 + bias[col], 256 blocks)
// Pipeline: prep | QK | Vt | scores | PV | out.

typedef __attribute__((ext_vector_type(8))) short short8;
typedef __attribute__((ext_vector_type(4))) float f32x4;
typedef __attribute__((ext_vector_type(4))) unsigned short us4;
typedef __attribute__((ext_vector_type(4))) float fl4;

__device__ __forceinline__ unsigned short f2b(float f) {
  unsigned int u = __builtin_bit_cast(unsigned int, f);
  u += 0x7fffu + ((u >> 16) & 1u);   // round-to-nearest-even
  return (unsigned short)(u >> 16);
}

// ---------------- merged prep: converts + bias packing + rowsum zero -------
__global__ __launch_bounds__(256) void prep_kernel(
    const float* __restrict__ x,
    const float* __restrict__ Wq, const float* __restrict__ Wk,
    const float* __restrict__ Wv, const float* __restrict__ Wo,
    const float* __restrict__ bq, const float* __restrict__ bk,
    const float* __restrict__ bv, const float* __restrict__ bo,
    unsigned short* __restrict__ xb, unsigned short* __restrict__ Wqkvb,
    unsigned short* __restrict__ Wob, float* __restrict__ bws,
    float* __restrict__ rows) {
  const int bid = blockIdx.x;
  if (bid < 8192) {
    const int i = bid * 256 + threadIdx.x;
    fl4 f = *(const fl4*)&x[(size_t)i << 2];
    us4 o;
#pragma unroll
    for (int j = 0; j < 4; ++j) o[j] = f2b(f[j]);
    *(us4*)&xb[(size_t)i << 2] = o;
  } else if (bid < 12288) {
    const int w = (bid - 8192) >> 10;
    const int i = ((bid - 8192) & 1023) * 256 + threadIdx.x;
    const float* s = w == 0 ? Wq : w == 1 ? Wk : w == 2 ? Wv : Wo;
    unsigned short* d = w < 3 ? Wqkvb + (size_t)w * 1024 * 1024 : Wob;
    fl4 f = *(const fl4*)&s[(size_t)i << 2];
    us4 o;
#pragma unroll
    for (int j = 0; j < 4; ++j) o[j] = f2b(f[j]);
    *(us4*)&d[(size_t)i << 2] = o;
  } else if (bid < 12304) {
    const int i = (bid - 12288) * 256 + threadIdx.x;
    const int sel = i >> 10, idx = i & 1023;
    const float* p = sel == 0 ? bq : sel == 1 ? bk : sel == 2 ? bv : bo;
    bws[i] = p[idx];
  } else {
    for (int k = threadIdx.x; k < 8192; k += 256) rows[k] = 0.f;
  }
}

#define RD_A(dst, basep)                                                   \
  _Pragma("unroll") for (int mi = 0; mi < 4; ++mi)                         \
  _Pragma("unroll") for (int ks = 0; ks < 2; ++ks)                         \
      dst[mi][ks] = *(const short8*)((basep) + offA[mi][ks]);

#define RD_B(dst, basep)                                                   \
  _Pragma("unroll") for (int nj = 0; nj < 2; ++nj)                         \
  _Pragma("unroll") for (int ks = 0; ks < 2; ++ks)                         \
      dst[nj][ks] = *(const short8*)((basep) + offB[nj][ks]);

#define MFMA16(AF, BF, MI0, NJ0)                                           \
  __builtin_amdgcn_s_setprio(1);                                           \
  _Pragma("unroll") for (int ks = 0; ks < 2; ++ks)                         \
  _Pragma("unroll") for (int mi = 0; mi < 4; ++mi)                         \
  _Pragma("unroll") for (int nj = 0; nj < 2; ++nj)                         \
      acc[(MI0) + mi][(NJ0) + nj] = __builtin_amdgcn_mfma_f32_16x16x32_bf16( \
          AF[mi][ks], BF[nj][ks], acc[(MI0) + mi][(NJ0) + nj], 0, 0, 0);   \
  __builtin_amdgcn_s_setprio(0);

// ---------------- g2: 256x128 2-phase pipelined B^T GEMM ----------------
// C[m][n] = sum_k A[m][k]*B[n][k], epilogue per EPI. 8 waves (2M x 4N),
// per-wave output 128x32. Loop identical to r13's measured gemm2ph.
template<int EPI>
__global__ __launch_bounds__(512, 2)
void g2(const unsigned short* __restrict__ A, const unsigned short* __restrict__ B,
        void* __restrict__ Cout, const float* __restrict__ bias,
        float* __restrict__ rows, float scale, int K,
        int lda, int ldb, int ldc,
        long long sAz, long long sBz, long long sCz)
{
  int m0, n0, z = 0, kEnd = K;
  if (EPI == 6) {
    // scores: 1-D tri grid, 288 = 4 batches x 72 (rows of 256, cols of 128)
    int id = (blockIdx.x & 7) * (gridDim.x >> 3) + (blockIdx.x >> 3);
    z = id / 72;
    int t = id % 72, mi = 0;
    while ((mi + 1) * (mi + 2) <= t) ++mi;     // cum(mi) = mi*(mi+1)
    m0 = mi << 8;
    n0 = (t - mi * (mi + 1)) << 7;
  } else if (EPI == 7) {
    // PV: 1-D 256 = 4 z x 8 my x 8 nc; causal clamp
    int id = (blockIdx.x & 7) * (gridDim.x >> 3) + (blockIdx.x >> 3);
    z = id >> 6;
    const int my = (id >> 3) & 7;
    m0 = my << 8;
    n0 = (id & 7) << 7;
    kEnd = (my + 1) << 8;
  } else {
    const int gx = gridDim.x;
    const int nwg = gx * gridDim.y;
    int flat = blockIdx.y * gx + blockIdx.x;
    { const int q = nwg >> 3, r = nwg & 7, xc = flat & 7, i = flat >> 3;
      flat = (xc < r ? xc * (q + 1) : r * (q + 1) + (xc - r) * q) + i; }
    m0 = (flat / gx) << 8;
    n0 = (flat % gx) << 7;
  }
  const int nt = kEnd >> 6;

  __shared__ unsigned short lA[2][2][8192];   // 64 KB
  __shared__ unsigned short lB[2][8192];      // 32 KB

  const int tid = threadIdx.x, lane = tid & 63, wid = tid >> 6;
  const int wm = wid >> 2, wn = wid & 3;
  const int fr = lane & 15, kg = lane >> 4;

  const unsigned short* Ab = A + (size_t)z * sAz;
  const unsigned short* Bb = B + (size_t)z * sBz;

  const int xorv = (fr & 7) << 4;
  int offA[4][2], offB[2][2];
#pragma unroll
  for (int mi = 0; mi < 4; ++mi)
#pragma unroll
    for (int ks = 0; ks < 2; ++ks)
      offA[mi][ks] = ((wm << 6) + (mi << 4) + fr) * 128 + (((ks << 6) + (kg << 4)) ^ xorv);
#pragma unroll
  for (int nj = 0; nj < 2; ++nj)
#pragma unroll
    for (int ks = 0; ks < 2; ++ks)
      offB[nj][ks] = ((wn << 5) + (nj << 4) + fr) * 128 + (((ks << 6) + (kg << 4)) ^ xorv);

  const int srow = tid >> 3;
  const int scol = (((tid & 7) ^ (srow & 7)) << 3);
  const unsigned short* aS = Ab + (size_t)(m0 + srow) * lda + scol;
  const unsigned short* bS = Bb + (size_t)(n0 + srow) * ldb + scol;

  auto stA = [&](int buf, int h, int tt) {
    int ttc = tt < nt ? tt : nt - 1;
    const unsigned short* s0 = aS + (size_t)(h << 7) * lda + (ttc << 6);
#pragma unroll
    for (int c = 0; c < 2; ++c)
      __builtin_amdgcn_global_load_lds(
          (const __attribute__((address_space(1))) void*)(s0 + (size_t)(c << 6) * lda),
          (__attribute__((address_space(3))) void*)((char*)&lA[buf][h][0] + (c << 13) + (tid << 4)),
          16, 0, 0);
  };
  auto stB = [&](int buf, int tt) {
    int ttc = tt < nt ? tt : nt - 1;
    const unsigned short* s0 = bS + (ttc << 6);
#pragma unroll
    for (int c = 0; c < 2; ++c)
      __builtin_amdgcn_global_load_lds(
          (const __attribute__((address_space(1))) void*)(s0 + (size_t)(c << 6) * ldb),
          (__attribute__((address_space(3))) void*)((char*)&lB[buf][0] + (c << 13) + (tid << 4)),
          16, 0, 0);
  };

  f32x4 acc[8][2];
#pragma unroll
  for (int i = 0; i < 8; ++i)
#pragma unroll
    for (int j = 0; j < 2; ++j) acc[i][j] = f32x4{0.f, 0.f, 0.f, 0.f};

  // prologue: tile0 B + Ah0 + Ah1 (6 loads); wait B+Ah0, leave Ah1 flying
  stB(0, 0); stA(0, 0, 0); stA(0, 1, 0);
  asm volatile("s_waitcnt vmcnt(2)" ::: "memory");
  __builtin_amdgcn_s_barrier();

  for (int t = 0; t < nt; ++t) {
    const int buf = t & 1, nbuf = buf ^ 1;
    const char* Ab0 = (const char*)&lA[buf][0][0];
    const char* Ab1 = (const char*)&lA[buf][1][0];
    const char* Bbp = (const char*)&lB[buf][0];

    short8 a0[4][2], a1[4][2], b0[2][2];

    // q0: reads B+Ah0; stage t+1 B+Ah0 (4); vmcnt(4) waits t's Ah1; BAR; MFMA
    RD_A(a0, Ab0);
    RD_B(b0, Bbp);
    stB(nbuf, t + 1); stA(nbuf, 0, t + 1);
    asm volatile("s_waitcnt vmcnt(4)" ::: "memory");
    __builtin_amdgcn_s_barrier();
    MFMA16(a0, b0, 0, 0);
    __builtin_amdgcn_s_barrier();

    // q1: reads Ah1; stage t+1 Ah1 (2); vmcnt(2) waits t+1's B+Ah0; BAR; MFMA
    RD_A(a1, Ab1);
    stA(nbuf, 1, t + 1);
    asm volatile("s_waitcnt vmcnt(2)" ::: "memory");
    __builtin_amdgcn_s_barrier();
    MFMA16(a1, b0, 4, 0);
    __builtin_amdgcn_s_barrier();
  }
  asm volatile("s_waitcnt vmcnt(0)" ::: "memory");

  // epilogue: C frag col=lane&15, row=(lane>>4)*4+reg
  if (EPI == 6) {
    unsigned short* Ch = (unsigned short*)Cout + (size_t)z * sCz;
#pragma unroll
    for (int mig = 0; mig < 8; ++mig) {
      const int row = m0 + (mig >> 2) * 128 + wm * 64 + (mig & 3) * 16 + (kg << 2);
#pragma unroll
      for (int jj = 0; jj < 4; ++jj) {
        const int r = row + jj;
        float rs = 0.f;
#pragma unroll
        for (int njg = 0; njg < 2; ++njg) {
          const int col = n0 + wn * 32 + njg * 16 + fr;
          const float ee = (col <= r) ? __expf(acc[mig][njg][jj] * scale) : 0.f;
          rs += ee;
          Ch[(size_t)r * ldc + col] = f2b(ee);
        }
#pragma unroll
        for (int mk = 1; mk <= 8; mk <<= 1) rs += __shfl_xor(rs, mk, 64);
        if (fr == 0) atomicAdd(&rows[z * 2048 + r], rs);
      }
    }
    return;
  }
#pragma unroll
  for (int mig = 0; mig < 8; ++mig)
#pragma unroll
    for (int njg = 0; njg < 2; ++njg) {
      const int row = m0 + (mig >> 2) * 128 + wm * 64 + (mig & 3) * 16 + (kg << 2);
      const int col = n0 + wn * 32 + njg * 16 + fr;
      f32x4 v = acc[mig][njg];
      if (EPI == 2) {          // out-proj: f32 + bias[col]
        float* Cf = (float*)Cout;
        const float bb = bias[col];
#pragma unroll
        for (int jj = 0; jj < 4; ++jj)
          Cf[(size_t)(row + jj) * ldc + col] = v[jj] + bb;
      } else if (EPI == 3) {   // QK-proj: bf16 + bias[col]
        unsigned short* Ch = (unsigned short*)Cout;
        const float bb = bias[col];
#pragma unroll
        for (int jj = 0; jj < 4; ++jj)
          Ch[(size_t)(row + jj) * ldc + col] = f2b(v[jj] + bb);
      } else if (EPI == 4) {   // Vt-proj: bf16 + bias[row]
        unsigned short* Ch = (unsigned short*)Cout;
#pragma unroll
        for (int jj = 0; jj < 4; ++jj)
          Ch[(size_t)(row + jj) * ldc + col] = f2b(v[jj] + bias[row + jj]);
      } else {                 // EPI == 7: PV direct, * 1/rowsum, batch offset
        unsigned short* Ch = (unsigned short*)Cout + (size_t)z * sCz;
#pragma unroll
        for (int jj = 0; jj < 4; ++jj) {
          const float inv = 1.f / rows[z * 2048 + row + jj];
          Ch[(size_t)(row + jj) * ldc + col] = f2b(v[jj] * inv);
        }
      }
    }
}

// ---------------- host-side launch ----------------
extern "C" void kernel_launch(void* const* d_in, const int* in_sizes, int n_in,
                              void* d_out, int out_size, void* d_ws, size_t ws_size,
                              hipStream_t stream) {
  (void)in_sizes; (void)n_in; (void)out_size; (void)ws_size;
  const float* x  = (const float*)d_in[0];
  const float* Wq = (const float*)d_in[1];
  const float* bq = (const float*)d_in[2];
  const float* Wk = (const float*)d_in[3];
  const float* bk = (const float*)d_in[4];
  const float* Wv = (const float*)d_in[5];
  const float* bv = (const float*)d_in[6];
  const float* Wo = (const float*)d_in[7];
  const float* bo = (const float*)d_in[8];

  const int B = 4, T = 2048, C = 1024;
  const int M = B * T;                                   // 8192

  unsigned short* xb    = (unsigned short*)d_ws;         // M*C ; later attn
  unsigned short* Wqkvb = xb    + (size_t)M * C;         // [Wq|Wk|Wv]
  unsigned short* Wob   = Wqkvb + (size_t)3 * C * C;
  unsigned short* QK    = Wob   + (size_t)C * C;         // M*2C [Q|K]
  unsigned short* Vt    = QK    + (size_t)M * 2 * C;     // [1024][8192]
  unsigned short* S     = Vt    + (size_t)M * C;         // B*T*T e-values
  float*          bws   = (float*)(S + (size_t)B * T * T);
  float*          rowsum= bws + 4096;                    // 8192 f32
  unsigned short* attn  = xb;                            // xb dead after Vt-proj

  // 1. prep: converts + packing + rowsum zero
  prep_kernel<<<12305, 256, 0, stream>>>(x, Wq, Wk, Wv, Wo, bq, bk, bv, bo,
                                         xb, Wqkvb, Wob, bws, rowsum);

  // 2. QK projection: QK[t][0:2048] = x @ [Wq|Wk]^T + [bq|bk]  (512 blocks)
  g2<3><<<dim3(16, 32), 512, 0, stream>>>(
      xb, Wqkvb, QK, bws, nullptr, 1.f, C, C, C, 2 * C, 0LL, 0LL, 0LL);

  // 3. Vt = Wv @ x^T + bv[row]  (256 blocks)
  g2<4><<<dim3(64, 4), 512, 0, stream>>>(
      Wqkvb + (size_t)2 * C * C, xb, Vt, bws + 2 * C, nullptr, 1.f,
      C, C, C, M, 0LL, 0LL, 0LL);

  // 4. scores: S = exp(Q K^T / 32) causal-masked + rowsum  (288 tri blocks)
  g2<6><<<288, 512, 0, stream>>>(
      QK, QK + C, S, nullptr, rowsum, 0.03125f, C, 2 * C, 2 * C, T,
      (long long)T * 2 * C, (long long)T * 2 * C, (long long)T * T);

  // 5. PV direct: attn = (S @ V) / rowsum  (256 blocks, causal kEnd)
  g2<7><<<256, 512, 0, stream>>>(
      S, Vt, attn, nullptr, rowsum, 1.f, T, T, M, C,
      (long long)T * T, 2048LL, (long long)T * C);

  // 6. out = attn Wo^T + bo (f32)  (256 blocks)
  g2<2><<<dim3(8, 32), 512, 0, stream>>>(
      attn, Wob, d_out, bws + 3 * C, nullptr, 1.f, C, C, C, C, 0LL, 0LL, 0LL);
}

// Round 16
// 183.981 us; speedup vs baseline: 1.0621x; 1.0316x over previous
//
#include <hip/hip_runtime.h>

// Masked self-attention, B=4 T=2048 C=1024 (single head, head dim = C).
// ROUND-13 CONFIGURATION (measured best: 183.9 µs) — banked.
//  gemm8  : 256x256 / BK=64 / 8-wave 8-barrier pipelined, vmcnt(4)/K-tile.
//           EPI 3 = bf16+bias[col] (QK), 5 = split-K2 partial (PV),
//           6 = scores exp+rowsum (tri early-exit).
//  gemm2ph: 256x128 2-phase (Vt-proj bf16+bias[row]; out-proj f32+bias[col]).
// LDS swizzle: 16B-slot ^= (row&7), both-sides. T1 XCD-bijective swizzle.
// Softmax fused in scores epilogue; reduce_pv2 divides by rowsum.
// Pipeline: prep | QK | Vt | scores | PV splitK2 | reduce2 | out.

typedef __attribute__((ext_vector_type(8))) short short8;
typedef __attribute__((ext_vector_type(4))) float f32x4;
typedef __attribute__((ext_vector_type(4))) unsigned short us4;
typedef __attribute__((ext_vector_type(8))) unsigned short us8;
typedef __attribute__((ext_vector_type(4))) float fl4;

__device__ __forceinline__ unsigned short f2b(float f) {
  unsigned int u = __builtin_bit_cast(unsigned int, f);
  u += 0x7fffu + ((u >> 16) & 1u);   // round-to-nearest-even
  return (unsigned short)(u >> 16);
}
__device__ __forceinline__ float b2f(unsigned short h) {
  unsigned int u = ((unsigned int)h) << 16;
  return __builtin_bit_cast(float, u);
}

// ---------------- merged prep: converts + bias packing + rowsum zero -------
__global__ __launch_bounds__(256) void prep_kernel(
    const float* __restrict__ x,
    const float* __restrict__ Wq, const float* __restrict__ Wk,
    const float* __restrict__ Wv, const float* __restrict__ Wo,
    const float* __restrict__ bq, const float* __restrict__ bk,
    const float* __restrict__ bv, const float* __restrict__ bo,
    unsigned short* __restrict__ xb, unsigned short* __restrict__ Wqkvb,
    unsigned short* __restrict__ Wob, float* __restrict__ bws,
    float* __restrict__ rows) {
  const int bid = blockIdx.x;
  if (bid < 8192) {
    const int i = bid * 256 + threadIdx.x;
    fl4 f = *(const fl4*)&x[(size_t)i << 2];
    us4 o;
#pragma unroll
    for (int j = 0; j < 4; ++j) o[j] = f2b(f[j]);
    *(us4*)&xb[(size_t)i << 2] = o;
  } else if (bid < 12288) {
    const int w = (bid - 8192) >> 10;
    const int i = ((bid - 8192) & 1023) * 256 + threadIdx.x;
    const float* s = w == 0 ? Wq : w == 1 ? Wk : w == 2 ? Wv : Wo;
    unsigned short* d = w < 3 ? Wqkvb + (size_t)w * 1024 * 1024 : Wob;
    fl4 f = *(const fl4*)&s[(size_t)i << 2];
    us4 o;
#pragma unroll
    for (int j = 0; j < 4; ++j) o[j] = f2b(f[j]);
    *(us4*)&d[(size_t)i << 2] = o;
  } else if (bid < 12304) {
    const int i = (bid - 12288) * 256 + threadIdx.x;
    const int sel = i >> 10, idx = i & 1023;
    const float* p = sel == 0 ? bq : sel == 1 ? bk : sel == 2 ? bv : bo;
    bws[i] = p[idx];
  } else {
    for (int k = threadIdx.x; k < 8192; k += 256) rows[k] = 0.f;
  }
}

#define RD_A(dst, basep)                                                   \
  _Pragma("unroll") for (int mi = 0; mi < 4; ++mi)                         \
  _Pragma("unroll") for (int ks = 0; ks < 2; ++ks)                         \
      dst[mi][ks] = *(const short8*)((basep) + offA[mi][ks]);

#define RD_B(dst, basep)                                                   \
  _Pragma("unroll") for (int nj = 0; nj < 2; ++nj)                         \
  _Pragma("unroll") for (int ks = 0; ks < 2; ++ks)                         \
      dst[nj][ks] = *(const short8*)((basep) + offB[nj][ks]);

#define MFMA16(AF, BF, MI0, NJ0)                                           \
  __builtin_amdgcn_s_setprio(1);                                           \
  _Pragma("unroll") for (int ks = 0; ks < 2; ++ks)                         \
  _Pragma("unroll") for (int mi = 0; mi < 4; ++mi)                         \
  _Pragma("unroll") for (int nj = 0; nj < 2; ++nj)                         \
      acc[(MI0) + mi][(NJ0) + nj] = __builtin_amdgcn_mfma_f32_16x16x32_bf16( \
          AF[mi][ks], BF[nj][ks], acc[(MI0) + mi][(NJ0) + nj], 0, 0, 0);   \
  __builtin_amdgcn_s_setprio(0);

// 8-barrier pipelined K-loop (template barrier discipline: 2 barriers/phase).
#define KLOOP_BODY                                                         \
  stA(0, 0, 0); stB(0, 0, 0); stA(0, 1, 0); stB(0, 1, 0);                  \
  stB(1, 0, 1); stA(1, 1, 1);                                              \
  asm volatile("s_waitcnt vmcnt(4)" ::: "memory");                         \
  __builtin_amdgcn_s_barrier();                                            \
  for (int t = 0; t < nt; ++t) {                                           \
    const int buf = t & 1, nbuf = buf ^ 1;                                 \
    const char* Ab0 = (const char*)&lA[buf][0][0];                         \
    const char* Ab1 = (const char*)&lA[buf][1][0];                         \
    const char* Bb0 = (const char*)&lB[buf][0][0];                         \
    const char* Bb1 = (const char*)&lB[buf][1][0];                         \
    short8 a0[4][2], a1[4][2], b0[2][2], b1[2][2];                         \
    RD_A(a0, Ab0);                                                         \
    RD_B(b0, Bb0);                                                         \
    stB(nbuf, 1, t + 1);                                                   \
    __builtin_amdgcn_s_barrier();                                          \
    RD_A(a1, Ab1);                                                         \
    MFMA16(a0, b0, 0, 0);                                                  \
    __builtin_amdgcn_s_barrier();                                          \
    stA(nbuf, 0, t + 1);                                                   \
    __builtin_amdgcn_s_barrier();                                          \
    RD_B(b1, Bb1);                                                         \
    MFMA16(a1, b0, 4, 0);                                                  \
    __builtin_amdgcn_s_barrier();                                          \
    stB(buf, 0, t + 2);                                                    \
    __builtin_amdgcn_s_barrier();                                          \
    MFMA16(a1, b1, 4, 2);                                                  \
    __builtin_amdgcn_s_barrier();                                          \
    stA(buf, 1, t + 2);                                                    \
    asm volatile("s_waitcnt vmcnt(4)" ::: "memory");                       \
    __builtin_amdgcn_s_barrier();                                          \
    MFMA16(a0, b1, 0, 2);                                                  \
    __builtin_amdgcn_s_barrier();                                          \
  }                                                                        \
  asm volatile("s_waitcnt vmcnt(0)" ::: "memory");

// ---------------- gemm8: 256x256 8-barrier pipelined ----------------
// EPI: 3 = bf16 + bias[col]   5 = split-K2 bf16 partial (half -> P0|P1)
//      6 = scores: bf16 exp(v*scale) causal-masked + rowsum atomics
template<int EPI, bool SPLIT2, bool SKIP_UPPER>
__global__ __launch_bounds__(512, 2)
void gemm8(const unsigned short* __restrict__ A, const unsigned short* __restrict__ B,
           void* __restrict__ Cout, const float* __restrict__ bias,
           float* __restrict__ rows, float scale, int K,
           int lda, int ldb, int ldc,
           long long sAz, long long sBz, long long sCz)
{
  const int gx = gridDim.x;
  const int nwg = gx * gridDim.y;
  int flat = blockIdx.y * gx + blockIdx.x;
  { const int q = nwg >> 3, r = nwg & 7, xc = flat & 7, i = flat >> 3;
    flat = (xc < r ? xc * (q + 1) : r * (q + 1) + (xc - r) * q) + i; }
  const int m0 = (flat / gx) << 8;
  const int n0 = (flat % gx) << 8;
  if (SKIP_UPPER && n0 > m0 + 255) return;   // fully-masked score block
  const int zraw = blockIdx.z;
  const int z = SPLIT2 ? (zraw >> 1) : zraw;

  int kBeg = 0, kEnd = K;
  if (SPLIT2) {                        // balanced causal half (PV)
    const int kFull = m0 + 256;        // multiple of 256
    const int kMid = kFull >> 1;       // multiple of 128
    kBeg = (zraw & 1) ? kMid : 0;
    kEnd = (zraw & 1) ? kFull : kMid;
  }
  const int nt = (kEnd - kBeg) >> 6;

  __shared__ unsigned short lA[2][2][8192];
  __shared__ unsigned short lB[2][2][8192];

  const int tid = threadIdx.x, lane = tid & 63, wid = tid >> 6;
  const int wm = wid >> 2, wn = wid & 3;
  const int fr = lane & 15, kg = lane >> 4;

  const unsigned short* Ab = A + (size_t)z * sAz;
  const unsigned short* Bb = B + (size_t)z * sBz;

  const int xorv = (fr & 7) << 4;
  int offA[4][2], offB[2][2];
#pragma unroll
  for (int mi = 0; mi < 4; ++mi)
#pragma unroll
    for (int ks = 0; ks < 2; ++ks)
      offA[mi][ks] = ((wm << 6) + (mi << 4) + fr) * 128 + (((ks << 6) + (kg << 4)) ^ xorv);
#pragma unroll
  for (int nj = 0; nj < 2; ++nj)
#pragma unroll
    for (int ks = 0; ks < 2; ++ks)
      offB[nj][ks] = ((wn << 5) + (nj << 4) + fr) * 128 + (((ks << 6) + (kg << 4)) ^ xorv);

  const int srow = tid >> 3;
  const int scol = (((tid & 7) ^ (srow & 7)) << 3);
  const unsigned short* aS = Ab + (size_t)(m0 + srow) * lda + scol + kBeg;
  const unsigned short* bS = Bb + (size_t)(n0 + srow) * ldb + scol + kBeg;

  auto stA = [&](int buf, int h, int tt) {
    int ttc = tt < nt ? tt : nt - 1;
    const unsigned short* s0 = aS + (size_t)(h << 7) * lda + (ttc << 6);
#pragma unroll
    for (int c = 0; c < 2; ++c)
      __builtin_amdgcn_global_load_lds(
          (const __attribute__((address_space(1))) void*)(s0 + (size_t)(c << 6) * lda),
          (__attribute__((address_space(3))) void*)((char*)&lA[buf][h][0] + (c << 13) + (tid << 4)),
          16, 0, 0);
  };
  auto stB = [&](int buf, int h, int tt) {
    int ttc = tt < nt ? tt : nt - 1;
    const unsigned short* s0 = bS + (size_t)(h << 7) * ldb + (ttc << 6);
#pragma unroll
    for (int c = 0; c < 2; ++c)
      __builtin_amdgcn_global_load_lds(
          (const __attribute__((address_space(1))) void*)(s0 + (size_t)(c << 6) * ldb),
          (__attribute__((address_space(3))) void*)((char*)&lB[buf][h][0] + (c << 13) + (tid << 4)),
          16, 0, 0);
  };

  f32x4 acc[8][4];
#pragma unroll
  for (int i = 0; i < 8; ++i)
#pragma unroll
    for (int j = 0; j < 4; ++j) acc[i][j] = f32x4{0.f, 0.f, 0.f, 0.f};

  KLOOP_BODY

  if (EPI == 6) {
    unsigned short* Ch = (unsigned short*)Cout + (size_t)z * sCz;
#pragma unroll
    for (int mig = 0; mig < 8; ++mig) {
      const int row = m0 + (mig >> 2) * 128 + wm * 64 + (mig & 3) * 16 + (kg << 2);
#pragma unroll
      for (int jj = 0; jj < 4; ++jj) {
        const int r = row + jj;
        float rs = 0.f;
#pragma unroll
        for (int njg = 0; njg < 4; ++njg) {
          const int col = n0 + (njg >> 1) * 128 + wn * 32 + (njg & 1) * 16 + fr;
          const float ee = (col <= r) ? __expf(acc[mig][njg][jj] * scale) : 0.f;
          rs += ee;
          Ch[(size_t)r * ldc + col] = f2b(ee);
        }
#pragma unroll
        for (int mk = 1; mk <= 8; mk <<= 1) rs += __shfl_xor(rs, mk, 64);
        if (fr == 0) atomicAdd(&rows[z * 2048 + r], rs);
      }
    }
    return;
  }
#pragma unroll
  for (int mig = 0; mig < 8; ++mig)
#pragma unroll
    for (int njg = 0; njg < 4; ++njg) {
      const int row = m0 + (mig >> 2) * 128 + wm * 64 + (mig & 3) * 16 + (kg << 2);
      const int col = n0 + (njg >> 1) * 128 + wn * 32 + (njg & 1) * 16 + fr;
      f32x4 v = acc[mig][njg];
      if (EPI == 3) {
        unsigned short* Ch = (unsigned short*)Cout;
        const float bb = bias[col];
#pragma unroll
        for (int jj = 0; jj < 4; ++jj)
          Ch[(size_t)(row + jj) * ldc + col] = f2b(v[jj] + bb);
      } else {   // EPI == 5: split-K2 partial; half selects P0|P1
        unsigned short* Ch = (unsigned short*)Cout +
            (size_t)(zraw & 1) * 8388608 + (size_t)z * sCz;
#pragma unroll
        for (int jj = 0; jj < 4; ++jj)
          Ch[(size_t)(row + jj) * ldc + col] = f2b(v[jj]);
      }
    }
}

// ---------------- gemm2ph: 256x128 2-phase, 4-barrier ----------------
// EPI: 2 = f32 + bias[col] (out-proj)   4 = bf16 + bias[row] (Vt-proj)
template<int EPI>
__global__ __launch_bounds__(512, 2)
void gemm2ph(const unsigned short* __restrict__ A, const unsigned short* __restrict__ B,
             void* __restrict__ Cout, const float* __restrict__ bias,
             int K, int lda, int ldb, int ldc)
{
  const int gx = gridDim.x;
  const int nwg = gx * gridDim.y;
  int flat = blockIdx.y * gx + blockIdx.x;
  { const int q = nwg >> 3, r = nwg & 7, xc = flat & 7, i = flat >> 3;
    flat = (xc < r ? xc * (q + 1) : r * (q + 1) + (xc - r) * q) + i; }
  const int m0 = (flat / gx) << 8;
  const int n0 = (flat % gx) << 7;
  const int nt = K >> 6;

  __shared__ unsigned short lA[2][2][8192];   // 64 KB
  __shared__ unsigned short lB[2][8192];      // 32 KB

  const int tid = threadIdx.x, lane = tid & 63, wid = tid >> 6;
  const int wm = wid >> 2, wn = wid & 3;
  const int fr = lane & 15, kg = lane >> 4;

  const int xorv = (fr & 7) << 4;
  int offA[4][2], offB[2][2];
#pragma unroll
  for (int mi = 0; mi < 4; ++mi)
#pragma unroll
    for (int ks = 0; ks < 2; ++ks)
      offA[mi][ks] = ((wm << 6) + (mi << 4) + fr) * 128 + (((ks << 6) + (kg << 4)) ^ xorv);
#pragma unroll
  for (int nj = 0; nj < 2; ++nj)
#pragma unroll
    for (int ks = 0; ks < 2; ++ks)
      offB[nj][ks] = ((wn << 5) + (nj << 4) + fr) * 128 + (((ks << 6) + (kg << 4)) ^ xorv);

  const int srow = tid >> 3;
  const int scol = (((tid & 7) ^ (srow & 7)) << 3);
  const unsigned short* aS = A + (size_t)(m0 + srow) * lda + scol;
  const unsigned short* bS = B + (size_t)(n0 + srow) * ldb + scol;

  auto stA = [&](int buf, int h, int tt) {
    int ttc = tt < nt ? tt : nt - 1;
    const unsigned short* s0 = aS + (size_t)(h << 7) * lda + (ttc << 6);
#pragma unroll
    for (int c = 0; c < 2; ++c)
      __builtin_amdgcn_global_load_lds(
          (const __attribute__((address_space(1))) void*)(s0 + (size_t)(c << 6) * lda),
          (__attribute__((address_space(3))) void*)((char*)&lA[buf][h][0] + (c << 13) + (tid << 4)),
          16, 0, 0);
  };
  auto stB = [&](int buf, int tt) {
    int ttc = tt < nt ? tt : nt - 1;
    const unsigned short* s0 = bS + (ttc << 6);
#pragma unroll
    for (int c = 0; c < 2; ++c)
      __builtin_amdgcn_global_load_lds(
          (const __attribute__((address_space(1))) void*)(s0 + (size_t)(c << 6) * ldb),
          (__attribute__((address_space(3))) void*)((char*)&lB[buf][0] + (c << 13) + (tid << 4)),
          16, 0, 0);
  };

  f32x4 acc[8][2];
#pragma unroll
  for (int i = 0; i < 8; ++i)
#pragma unroll
    for (int j = 0; j < 2; ++j) acc[i][j] = f32x4{0.f, 0.f, 0.f, 0.f};

  stB(0, 0); stA(0, 0, 0); stA(0, 1, 0);
  asm volatile("s_waitcnt vmcnt(2)" ::: "memory");
  __builtin_amdgcn_s_barrier();

  for (int t = 0; t < nt; ++t) {
    const int buf = t & 1, nbuf = buf ^ 1;
    const char* Ab0 = (const char*)&lA[buf][0][0];
    const char* Ab1 = (const char*)&lA[buf][1][0];
    const char* Bbp = (const char*)&lB[buf][0];

    short8 a0[4][2], a1[4][2], b0[2][2];

    RD_A(a0, Ab0);
    RD_B(b0, Bbp);
    stB(nbuf, t + 1); stA(nbuf, 0, t + 1);
    asm volatile("s_waitcnt vmcnt(4)" ::: "memory");
    __builtin_amdgcn_s_barrier();
    MFMA16(a0, b0, 0, 0);
    __builtin_amdgcn_s_barrier();

    RD_A(a1, Ab1);
    stA(nbuf, 1, t + 1);
    asm volatile("s_waitcnt vmcnt(2)" ::: "memory");
    __builtin_amdgcn_s_barrier();
    MFMA16(a1, b0, 4, 0);
    __builtin_amdgcn_s_barrier();
  }
  asm volatile("s_waitcnt vmcnt(0)" ::: "memory");

#pragma unroll
  for (int mig = 0; mig < 8; ++mig)
#pragma unroll
    for (int njg = 0; njg < 2; ++njg) {
      const int row = m0 + (mig >> 2) * 128 + wm * 64 + (mig & 3) * 16 + (kg << 2);
      const int col = n0 + wn * 32 + njg * 16 + fr;
      f32x4 v = acc[mig][njg];
      if (EPI == 2) {
        float* Cf = (float*)Cout;
        const float bb = bias[col];
#pragma unroll
        for (int jj = 0; jj < 4; ++jj)
          Cf[(size_t)(row + jj) * ldc + col] = v[jj] + bb;
      } else {   // EPI == 4: bias by row (Vt-proj)
        unsigned short* Ch = (unsigned short*)Cout;
#pragma unroll
        for (int jj = 0; jj < 4; ++jj)
          Ch[(size_t)(row + jj) * ldc + col] = f2b(v[jj] + bias[row + jj]);
      }
    }
}

// -------- split-K2 reduce + normalize: attn = (P0+P1)/rowsum --------
__global__ __launch_bounds__(256)
void reduce_pv2(const unsigned short* __restrict__ p0,
                const unsigned short* __restrict__ p1,
                const float* __restrict__ rows,
                unsigned short* __restrict__ out) {
  const size_t i = ((size_t)blockIdx.x * 256 + threadIdx.x) << 3;
  const float inv = 1.f / rows[i >> 10];
  us8 a = *(const us8*)&p0[i];
  us8 b = *(const us8*)&p1[i];
  us8 o;
#pragma unroll
  for (int j = 0; j < 8; ++j)
    o[j] = f2b((b2f(a[j]) + b2f(b[j])) * inv);
  *(us8*)&out[i] = o;
}

// ---------------- host-side launch ----------------
extern "C" void kernel_launch(void* const* d_in, const int* in_sizes, int n_in,
                              void* d_out, int out_size, void* d_ws, size_t ws_size,
                              hipStream_t stream) {
  (void)in_sizes; (void)n_in; (void)out_size; (void)ws_size;
  const float* x  = (const float*)d_in[0];
  const float* Wq = (const float*)d_in[1];
  const float* bq = (const float*)d_in[2];
  const float* Wk = (const float*)d_in[3];
  const float* bk = (const float*)d_in[4];
  const float* Wv = (const float*)d_in[5];
  const float* bv = (const float*)d_in[6];
  const float* Wo = (const float*)d_in[7];
  const float* bo = (const float*)d_in[8];

  const int B = 4, T = 2048, C = 1024;
  const int M = B * T;                                   // 8192

  unsigned short* xb    = (unsigned short*)d_ws;         // M*C
  unsigned short* Wqkvb = xb    + (size_t)M * C;         // [Wq|Wk|Wv]
  unsigned short* Wob   = Wqkvb + (size_t)3 * C * C;
  unsigned short* QK    = Wob   + (size_t)C * C;         // M*2C [Q|K]; later P0|P1
  unsigned short* Vt    = QK    + (size_t)M * 2 * C;     // [1024][8192]
  unsigned short* S     = Vt    + (size_t)M * C;         // B*T*T e-values
  float*          bws   = (float*)(S + (size_t)B * T * T);
  float*          rowsum= bws + 4096;                    // 8192 f32
  unsigned short* P0    = QK;
  unsigned short* P1    = QK + (size_t)M * C;
  unsigned short* attn  = P0;

  // 1. prep
  prep_kernel<<<12305, 256, 0, stream>>>(x, Wq, Wk, Wv, Wo, bq, bk, bv, bo,
                                         xb, Wqkvb, Wob, bws, rowsum);

  // 2. QK projection (256 blocks)
  gemm8<3, false, false><<<dim3(2 * C / 256, M / 256, 1), 512, 0, stream>>>(
      xb, Wqkvb, QK, bws, nullptr, 1.f, C, C, C, 2 * C, 0LL, 0LL, 0LL);

  // 3. Vt = Wv @ x^T + bv[row] (256 blocks, BN=128)
  gemm2ph<4><<<dim3(M / 128, C / 256, 1), 512, 0, stream>>>(
      Wqkvb + (size_t)2 * C * C, xb, Vt, bws + 2 * C, C, C, C, M);

  // 4. scores: S = exp(Q K^T / 32) causal-masked + rowsum atomics
  gemm8<6, false, true><<<dim3(T / 256, T / 256, B), 512, 0, stream>>>(
      QK, QK + C, S, nullptr, rowsum, 0.03125f, C, 2 * C, 2 * C, T,
      (long long)T * 2 * C, (long long)T * 2 * C, (long long)T * T);

  // 5. PV split-K2: partials P0|P1 (z = batch*2 + half), 256 blocks
  gemm8<5, true, false><<<dim3(C / 256, T / 256, 2 * B), 512, 0, stream>>>(
      S, Vt, P0, nullptr, nullptr, 1.f, T, T, M, C,
      (long long)T * T, 2048LL, (long long)T * C);

  // 6. reduce + normalize (attn -> P0 in place)
  reduce_pv2<<<4096, 256, 0, stream>>>(P0, P1, rowsum, attn);

  // 7. out = attn Wo^T + bo (f32, 256 blocks BN=128)
  gemm2ph<2><<<dim3(C / 128, M / 256, 1), 512, 0, stream>>>(
      attn, Wob, d_out, bws + 3 * C, C, C, C, C);
}

// Round 17
// 183.097 us; speedup vs baseline: 1.0673x; 1.0048x over previous
//
#include <hip/hip_runtime.h>

// Masked self-attention, B=4 T=2048 C=1024 (single head, head dim = C).
// ROUND-13/16 CONFIGURATION (measured best: 183.9 µs, reproduced twice).
//  gemm8  : 256x256 / BK=64 / 8-wave 8-barrier pipelined, vmcnt(4)/K-tile.
//           EPI 3 = bf16+bias[col] (QK), 5 = split-K2 partial (PV),
//           6 = scores exp+rowsum (tri early-exit).
//  gemm2ph: 256x128 2-phase (Vt-proj bf16+bias[row]; out-proj f32+bias[col]).
// LDS swizzle: 16B-slot ^= (row&7), both-sides. T1 XCD-bijective swizzle.
// Softmax fused in scores epilogue; reduce_pv2 divides by rowsum.
// r17: prep + reduce converted to 2048-block grid-stride (G11); GEMMs
// byte-identical to the banked optimum.
// Pipeline: prep | QK | Vt | scores | PV splitK2 | reduce2 | out.

typedef __attribute__((ext_vector_type(8))) short short8;
typedef __attribute__((ext_vector_type(4))) float f32x4;
typedef __attribute__((ext_vector_type(4))) unsigned short us4;
typedef __attribute__((ext_vector_type(8))) unsigned short us8;
typedef __attribute__((ext_vector_type(4))) float fl4;

__device__ __forceinline__ unsigned short f2b(float f) {
  unsigned int u = __builtin_bit_cast(unsigned int, f);
  u += 0x7fffu + ((u >> 16) & 1u);   // round-to-nearest-even
  return (unsigned short)(u >> 16);
}
__device__ __forceinline__ float b2f(unsigned short h) {
  unsigned int u = ((unsigned int)h) << 16;
  return __builtin_bit_cast(float, u);
}

// ------- prep (grid-stride): converts + bias packing + rowsum zero -------
// Unified fl4 index space:
//   [0, 2097152)        : x -> xb            (8192*1024/4)
//   [2097152, 3145728)  : Wq|Wk|Wv|Wo -> bf16 (4 * 262144)
//   [3145728, 3146752)  : biases -> bws      (4096 f32 / 4)
//   [3146752, 3148800)  : rowsum = 0         (8192 f32 / 4)
__global__ __launch_bounds__(256) void prep_kernel(
    const float* __restrict__ x,
    const float* __restrict__ Wq, const float* __restrict__ Wk,
    const float* __restrict__ Wv, const float* __restrict__ Wo,
    const float* __restrict__ bq, const float* __restrict__ bk,
    const float* __restrict__ bv, const float* __restrict__ bo,
    unsigned short* __restrict__ xb, unsigned short* __restrict__ Wqkvb,
    unsigned short* __restrict__ Wob, float* __restrict__ bws,
    float* __restrict__ rows) {
  const unsigned stride = gridDim.x * 256u;
  for (unsigned i = blockIdx.x * 256u + threadIdx.x; i < 3148800u; i += stride) {
    if (i < 2097152u) {
      fl4 f = *(const fl4*)&x[(size_t)i << 2];
      us4 o;
#pragma unroll
      for (int j = 0; j < 4; ++j) o[j] = f2b(f[j]);
      *(us4*)&xb[(size_t)i << 2] = o;
    } else if (i < 3145728u) {
      const unsigned k = i - 2097152u;
      const int w = k >> 18;                    // 262144 fl4 per weight
      const unsigned idx = k & 262143u;
      const float* s = w == 0 ? Wq : w == 1 ? Wk : w == 2 ? Wv : Wo;
      unsigned short* d = w < 3 ? Wqkvb + (size_t)w * 1024 * 1024 : Wob;
      fl4 f = *(const fl4*)&s[(size_t)idx << 2];
      us4 o;
#pragma unroll
      for (int j = 0; j < 4; ++j) o[j] = f2b(f[j]);
      *(us4*)&d[(size_t)idx << 2] = o;
    } else if (i < 3146752u) {
      const unsigned j = i - 3145728u;          // fl4 index into bws[4096]
      const int sel = j >> 8;
      const unsigned within = j & 255u;
      const float* p = sel == 0 ? bq : sel == 1 ? bk : sel == 2 ? bv : bo;
      *(fl4*)&bws[(size_t)j << 2] = *(const fl4*)&p[(size_t)within << 2];
    } else {
      const unsigned j = i - 3146752u;          // fl4 index into rowsum[8192]
      *(fl4*)&rows[(size_t)j << 2] = fl4{0.f, 0.f, 0.f, 0.f};
    }
  }
}

#define RD_A(dst, basep)                                                   \
  _Pragma("unroll") for (int mi = 0; mi < 4; ++mi)                         \
  _Pragma("unroll") for (int ks = 0; ks < 2; ++ks)                         \
      dst[mi][ks] = *(const short8*)((basep) + offA[mi][ks]);

#define RD_B(dst, basep)                                                   \
  _Pragma("unroll") for (int nj = 0; nj < 2; ++nj)                         \
  _Pragma("unroll") for (int ks = 0; ks < 2; ++ks)                         \
      dst[nj][ks] = *(const short8*)((basep) + offB[nj][ks]);

#define MFMA16(AF, BF, MI0, NJ0)                                           \
  __builtin_amdgcn_s_setprio(1);                                           \
  _Pragma("unroll") for (int ks = 0; ks < 2; ++ks)                         \
  _Pragma("unroll") for (int mi = 0; mi < 4; ++mi)                         \
  _Pragma("unroll") for (int nj = 0; nj < 2; ++nj)                         \
      acc[(MI0) + mi][(NJ0) + nj] = __builtin_amdgcn_mfma_f32_16x16x32_bf16( \
          AF[mi][ks], BF[nj][ks], acc[(MI0) + mi][(NJ0) + nj], 0, 0, 0);   \
  __builtin_amdgcn_s_setprio(0);

// 8-barrier pipelined K-loop (template barrier discipline: 2 barriers/phase).
#define KLOOP_BODY                                                         \
  stA(0, 0, 0); stB(0, 0, 0); stA(0, 1, 0); stB(0, 1, 0);                  \
  stB(1, 0, 1); stA(1, 1, 1);                                              \
  asm volatile("s_waitcnt vmcnt(4)" ::: "memory");                         \
  __builtin_amdgcn_s_barrier();                                            \
  for (int t = 0; t < nt; ++t) {                                           \
    const int buf = t & 1, nbuf = buf ^ 1;                                 \
    const char* Ab0 = (const char*)&lA[buf][0][0];                         \
    const char* Ab1 = (const char*)&lA[buf][1][0];                         \
    const char* Bb0 = (const char*)&lB[buf][0][0];                         \
    const char* Bb1 = (const char*)&lB[buf][1][0];                         \
    short8 a0[4][2], a1[4][2], b0[2][2], b1[2][2];                         \
    RD_A(a0, Ab0);                                                         \
    RD_B(b0, Bb0);                                                         \
    stB(nbuf, 1, t + 1);                                                   \
    __builtin_amdgcn_s_barrier();                                          \
    RD_A(a1, Ab1);                                                         \
    MFMA16(a0, b0, 0, 0);                                                  \
    __builtin_amdgcn_s_barrier();                                          \
    stA(nbuf, 0, t + 1);                                                   \
    __builtin_amdgcn_s_barrier();                                          \
    RD_B(b1, Bb1);                                                         \
    MFMA16(a1, b0, 4, 0);                                                  \
    __builtin_amdgcn_s_barrier();                                          \
    stB(buf, 0, t + 2);                                                    \
    __builtin_amdgcn_s_barrier();                                          \
    MFMA16(a1, b1, 4, 2);                                                  \
    __builtin_amdgcn_s_barrier();                                          \
    stA(buf, 1, t + 2);                                                    \
    asm volatile("s_waitcnt vmcnt(4)" ::: "memory");                       \
    __builtin_amdgcn_s_barrier();                                          \
    MFMA16(a0, b1, 0, 2);                                                  \
    __builtin_amdgcn_s_barrier();                                          \
  }                                                                        \
  asm volatile("s_waitcnt vmcnt(0)" ::: "memory");

// ---------------- gemm8: 256x256 8-barrier pipelined ----------------
// EPI: 3 = bf16 + bias[col]   5 = split-K2 bf16 partial (half -> P0|P1)
//      6 = scores: bf16 exp(v*scale) causal-masked + rowsum atomics
template<int EPI, bool SPLIT2, bool SKIP_UPPER>
__global__ __launch_bounds__(512, 2)
void gemm8(const unsigned short* __restrict__ A, const unsigned short* __restrict__ B,
           void* __restrict__ Cout, const float* __restrict__ bias,
           float* __restrict__ rows, float scale, int K,
           int lda, int ldb, int ldc,
           long long sAz, long long sBz, long long sCz)
{
  const int gx = gridDim.x;
  const int nwg = gx * gridDim.y;
  int flat = blockIdx.y * gx + blockIdx.x;
  { const int q = nwg >> 3, r = nwg & 7, xc = flat & 7, i = flat >> 3;
    flat = (xc < r ? xc * (q + 1) : r * (q + 1) + (xc - r) * q) + i; }
  const int m0 = (flat / gx) << 8;
  const int n0 = (flat % gx) << 8;
  if (SKIP_UPPER && n0 > m0 + 255) return;   // fully-masked score block
  const int zraw = blockIdx.z;
  const int z = SPLIT2 ? (zraw >> 1) : zraw;

  int kBeg = 0, kEnd = K;
  if (SPLIT2) {                        // balanced causal half (PV)
    const int kFull = m0 + 256;        // multiple of 256
    const int kMid = kFull >> 1;       // multiple of 128
    kBeg = (zraw & 1) ? kMid : 0;
    kEnd = (zraw & 1) ? kFull : kMid;
  }
  const int nt = (kEnd - kBeg) >> 6;

  __shared__ unsigned short lA[2][2][8192];
  __shared__ unsigned short lB[2][2][8192];

  const int tid = threadIdx.x, lane = tid & 63, wid = tid >> 6;
  const int wm = wid >> 2, wn = wid & 3;
  const int fr = lane & 15, kg = lane >> 4;

  const unsigned short* Ab = A + (size_t)z * sAz;
  const unsigned short* Bb = B + (size_t)z * sBz;

  const int xorv = (fr & 7) << 4;
  int offA[4][2], offB[2][2];
#pragma unroll
  for (int mi = 0; mi < 4; ++mi)
#pragma unroll
    for (int ks = 0; ks < 2; ++ks)
      offA[mi][ks] = ((wm << 6) + (mi << 4) + fr) * 128 + (((ks << 6) + (kg << 4)) ^ xorv);
#pragma unroll
  for (int nj = 0; nj < 2; ++nj)
#pragma unroll
    for (int ks = 0; ks < 2; ++ks)
      offB[nj][ks] = ((wn << 5) + (nj << 4) + fr) * 128 + (((ks << 6) + (kg << 4)) ^ xorv);

  const int srow = tid >> 3;
  const int scol = (((tid & 7) ^ (srow & 7)) << 3);
  const unsigned short* aS = Ab + (size_t)(m0 + srow) * lda + scol + kBeg;
  const unsigned short* bS = Bb + (size_t)(n0 + srow) * ldb + scol + kBeg;

  auto stA = [&](int buf, int h, int tt) {
    int ttc = tt < nt ? tt : nt - 1;
    const unsigned short* s0 = aS + (size_t)(h << 7) * lda + (ttc << 6);
#pragma unroll
    for (int c = 0; c < 2; ++c)
      __builtin_amdgcn_global_load_lds(
          (const __attribute__((address_space(1))) void*)(s0 + (size_t)(c << 6) * lda),
          (__attribute__((address_space(3))) void*)((char*)&lA[buf][h][0] + (c << 13) + (tid << 4)),
          16, 0, 0);
  };
  auto stB = [&](int buf, int h, int tt) {
    int ttc = tt < nt ? tt : nt - 1;
    const unsigned short* s0 = bS + (size_t)(h << 7) * ldb + (ttc << 6);
#pragma unroll
    for (int c = 0; c < 2; ++c)
      __builtin_amdgcn_global_load_lds(
          (const __attribute__((address_space(1))) void*)(s0 + (size_t)(c << 6) * ldb),
          (__attribute__((address_space(3))) void*)((char*)&lB[buf][h][0] + (c << 13) + (tid << 4)),
          16, 0, 0);
  };

  f32x4 acc[8][4];
#pragma unroll
  for (int i = 0; i < 8; ++i)
#pragma unroll
    for (int j = 0; j < 4; ++j) acc[i][j] = f32x4{0.f, 0.f, 0.f, 0.f};

  KLOOP_BODY

  if (EPI == 6) {
    unsigned short* Ch = (unsigned short*)Cout + (size_t)z * sCz;
#pragma unroll
    for (int mig = 0; mig < 8; ++mig) {
      const int row = m0 + (mig >> 2) * 128 + wm * 64 + (mig & 3) * 16 + (kg << 2);
#pragma unroll
      for (int jj = 0; jj < 4; ++jj) {
        const int r = row + jj;
        float rs = 0.f;
#pragma unroll
        for (int njg = 0; njg < 4; ++njg) {
          const int col = n0 + (njg >> 1) * 128 + wn * 32 + (njg & 1) * 16 + fr;
          const float ee = (col <= r) ? __expf(acc[mig][njg][jj] * scale) : 0.f;
          rs += ee;
          Ch[(size_t)r * ldc + col] = f2b(ee);
        }
#pragma unroll
        for (int mk = 1; mk <= 8; mk <<= 1) rs += __shfl_xor(rs, mk, 64);
        if (fr == 0) atomicAdd(&rows[z * 2048 + r], rs);
      }
    }
    return;
  }
#pragma unroll
  for (int mig = 0; mig < 8; ++mig)
#pragma unroll
    for (int njg = 0; njg < 4; ++njg) {
      const int row = m0 + (mig >> 2) * 128 + wm * 64 + (mig & 3) * 16 + (kg << 2);
      const int col = n0 + (njg >> 1) * 128 + wn * 32 + (njg & 1) * 16 + fr;
      f32x4 v = acc[mig][njg];
      if (EPI == 3) {
        unsigned short* Ch = (unsigned short*)Cout;
        const float bb = bias[col];
#pragma unroll
        for (int jj = 0; jj < 4; ++jj)
          Ch[(size_t)(row + jj) * ldc + col] = f2b(v[jj] + bb);
      } else {   // EPI == 5: split-K2 partial; half selects P0|P1
        unsigned short* Ch = (unsigned short*)Cout +
            (size_t)(zraw & 1) * 8388608 + (size_t)z * sCz;
#pragma unroll
        for (int jj = 0; jj < 4; ++jj)
          Ch[(size_t)(row + jj) * ldc + col] = f2b(v[jj]);
      }
    }
}

// ---------------- gemm2ph: 256x128 2-phase, 4-barrier ----------------
// EPI: 2 = f32 + bias[col] (out-proj)   4 = bf16 + bias[row] (Vt-proj)
template<int EPI>
__global__ __launch_bounds__(512, 2)
void gemm2ph(const unsigned short* __restrict__ A, const unsigned short* __restrict__ B,
             void* __restrict__ Cout, const float* __restrict__ bias,
             int K, int lda, int ldb, int ldc)
{
  const int gx = gridDim.x;
  const int nwg = gx * gridDim.y;
  int flat = blockIdx.y * gx + blockIdx.x;
  { const int q = nwg >> 3, r = nwg & 7, xc = flat & 7, i = flat >> 3;
    flat = (xc < r ? xc * (q + 1) : r * (q + 1) + (xc - r) * q) + i; }
  const int m0 = (flat / gx) << 8;
  const int n0 = (flat % gx) << 7;
  const int nt = K >> 6;

  __shared__ unsigned short lA[2][2][8192];   // 64 KB
  __shared__ unsigned short lB[2][8192];      // 32 KB

  const int tid = threadIdx.x, lane = tid & 63, wid = tid >> 6;
  const int wm = wid >> 2, wn = wid & 3;
  const int fr = lane & 15, kg = lane >> 4;

  const int xorv = (fr & 7) << 4;
  int offA[4][2], offB[2][2];
#pragma unroll
  for (int mi = 0; mi < 4; ++mi)
#pragma unroll
    for (int ks = 0; ks < 2; ++ks)
      offA[mi][ks] = ((wm << 6) + (mi << 4) + fr) * 128 + (((ks << 6) + (kg << 4)) ^ xorv);
#pragma unroll
  for (int nj = 0; nj < 2; ++nj)
#pragma unroll
    for (int ks = 0; ks < 2; ++ks)
      offB[nj][ks] = ((wn << 5) + (nj << 4) + fr) * 128 + (((ks << 6) + (kg << 4)) ^ xorv);

  const int srow = tid >> 3;
  const int scol = (((tid & 7) ^ (srow & 7)) << 3);
  const unsigned short* aS = A + (size_t)(m0 + srow) * lda + scol;
  const unsigned short* bS = B + (size_t)(n0 + srow) * ldb + scol;

  auto stA = [&](int buf, int h, int tt) {
    int ttc = tt < nt ? tt : nt - 1;
    const unsigned short* s0 = aS + (size_t)(h << 7) * lda + (ttc << 6);
#pragma unroll
    for (int c = 0; c < 2; ++c)
      __builtin_amdgcn_global_load_lds(
          (const __attribute__((address_space(1))) void*)(s0 + (size_t)(c << 6) * lda),
          (__attribute__((address_space(3))) void*)((char*)&lA[buf][h][0] + (c << 13) + (tid << 4)),
          16, 0, 0);
  };
  auto stB = [&](int buf, int tt) {
    int ttc = tt < nt ? tt : nt - 1;
    const unsigned short* s0 = bS + (ttc << 6);
#pragma unroll
    for (int c = 0; c < 2; ++c)
      __builtin_amdgcn_global_load_lds(
          (const __attribute__((address_space(1))) void*)(s0 + (size_t)(c << 6) * ldb),
          (__attribute__((address_space(3))) void*)((char*)&lB[buf][0] + (c << 13) + (tid << 4)),
          16, 0, 0);
  };

  f32x4 acc[8][2];
#pragma unroll
  for (int i = 0; i < 8; ++i)
#pragma unroll
    for (int j = 0; j < 2; ++j) acc[i][j] = f32x4{0.f, 0.f, 0.f, 0.f};

  stB(0, 0); stA(0, 0, 0); stA(0, 1, 0);
  asm volatile("s_waitcnt vmcnt(2)" ::: "memory");
  __builtin_amdgcn_s_barrier();

  for (int t = 0; t < nt; ++t) {
    const int buf = t & 1, nbuf = buf ^ 1;
    const char* Ab0 = (const char*)&lA[buf][0][0];
    const char* Ab1 = (const char*)&lA[buf][1][0];
    const char* Bbp = (const char*)&lB[buf][0];

    short8 a0[4][2], a1[4][2], b0[2][2];

    RD_A(a0, Ab0);
    RD_B(b0, Bbp);
    stB(nbuf, t + 1); stA(nbuf, 0, t + 1);
    asm volatile("s_waitcnt vmcnt(4)" ::: "memory");
    __builtin_amdgcn_s_barrier();
    MFMA16(a0, b0, 0, 0);
    __builtin_amdgcn_s_barrier();

    RD_A(a1, Ab1);
    stA(nbuf, 1, t + 1);
    asm volatile("s_waitcnt vmcnt(2)" ::: "memory");
    __builtin_amdgcn_s_barrier();
    MFMA16(a1, b0, 4, 0);
    __builtin_amdgcn_s_barrier();
  }
  asm volatile("s_waitcnt vmcnt(0)" ::: "memory");

#pragma unroll
  for (int mig = 0; mig < 8; ++mig)
#pragma unroll
    for (int njg = 0; njg < 2; ++njg) {
      const int row = m0 + (mig >> 2) * 128 + wm * 64 + (mig & 3) * 16 + (kg << 2);
      const int col = n0 + wn * 32 + njg * 16 + fr;
      f32x4 v = acc[mig][njg];
      if (EPI == 2) {
        float* Cf = (float*)Cout;
        const float bb = bias[col];
#pragma unroll
        for (int jj = 0; jj < 4; ++jj)
          Cf[(size_t)(row + jj) * ldc + col] = v[jj] + bb;
      } else {   // EPI == 4: bias by row (Vt-proj)
        unsigned short* Ch = (unsigned short*)Cout;
#pragma unroll
        for (int jj = 0; jj < 4; ++jj)
          Ch[(size_t)(row + jj) * ldc + col] = f2b(v[jj] + bias[row + jj]);
      }
    }
}

// ---- split-K2 reduce + normalize (grid-stride): attn = (P0+P1)/rowsum ----
__global__ __launch_bounds__(256)
void reduce_pv2(const unsigned short* __restrict__ p0,
                const unsigned short* __restrict__ p1,
                const float* __restrict__ rows,
                unsigned short* __restrict__ out) {
  const unsigned stride = gridDim.x * 256u;
  for (unsigned g = blockIdx.x * 256u + threadIdx.x; g < 1048576u; g += stride) {
    const size_t i = (size_t)g << 3;
    const float inv = 1.f / rows[i >> 10];
    us8 a = *(const us8*)&p0[i];
    us8 b = *(const us8*)&p1[i];
    us8 o;
#pragma unroll
    for (int j = 0; j < 8; ++j)
      o[j] = f2b((b2f(a[j]) + b2f(b[j])) * inv);
    *(us8*)&out[i] = o;
  }
}

// ---------------- host-side launch ----------------
extern "C" void kernel_launch(void* const* d_in, const int* in_sizes, int n_in,
                              void* d_out, int out_size, void* d_ws, size_t ws_size,
                              hipStream_t stream) {
  (void)in_sizes; (void)n_in; (void)out_size; (void)ws_size;
  const float* x  = (const float*)d_in[0];
  const float* Wq = (const float*)d_in[1];
  const float* bq = (const float*)d_in[2];
  const float* Wk = (const float*)d_in[3];
  const float* bk = (const float*)d_in[4];
  const float* Wv = (const float*)d_in[5];
  const float* bv = (const float*)d_in[6];
  const float* Wo = (const float*)d_in[7];
  const float* bo = (const float*)d_in[8];

  const int B = 4, T = 2048, C = 1024;
  const int M = B * T;                                   // 8192

  unsigned short* xb    = (unsigned short*)d_ws;         // M*C
  unsigned short* Wqkvb = xb    + (size_t)M * C;         // [Wq|Wk|Wv]
  unsigned short* Wob   = Wqkvb + (size_t)3 * C * C;
  unsigned short* QK    = Wob   + (size_t)C * C;         // M*2C [Q|K]; later P0|P1
  unsigned short* Vt    = QK    + (size_t)M * 2 * C;     // [1024][8192]
  unsigned short* S     = Vt    + (size_t)M * C;         // B*T*T e-values
  float*          bws   = (float*)(S + (size_t)B * T * T);
  float*          rowsum= bws + 4096;                    // 8192 f32
  unsigned short* P0    = QK;
  unsigned short* P1    = QK + (size_t)M * C;
  unsigned short* attn  = P0;

  // 1. prep (grid-stride, 2048 blocks)
  prep_kernel<<<2048, 256, 0, stream>>>(x, Wq, Wk, Wv, Wo, bq, bk, bv, bo,
                                        xb, Wqkvb, Wob, bws, rowsum);

  // 2. QK projection (256 blocks)
  gemm8<3, false, false><<<dim3(2 * C / 256, M / 256, 1), 512, 0, stream>>>(
      xb, Wqkvb, QK, bws, nullptr, 1.f, C, C, C, 2 * C, 0LL, 0LL, 0LL);

  // 3. Vt = Wv @ x^T + bv[row] (256 blocks, BN=128)
  gemm2ph<4><<<dim3(M / 128, C / 256, 1), 512, 0, stream>>>(
      Wqkvb + (size_t)2 * C * C, xb, Vt, bws + 2 * C, C, C, C, M);

  // 4. scores: S = exp(Q K^T / 32) causal-masked + rowsum atomics
  gemm8<6, false, true><<<dim3(T / 256, T / 256, B), 512, 0, stream>>>(
      QK, QK + C, S, nullptr, rowsum, 0.03125f, C, 2 * C, 2 * C, T,
      (long long)T * 2 * C, (long long)T * 2 * C, (long long)T * T);

  // 5. PV split-K2: partials P0|P1 (z = batch*2 + half), 256 blocks
  gemm8<5, true, false><<<dim3(C / 256, T / 256, 2 * B), 512, 0, stream>>>(
      S, Vt, P0, nullptr, nullptr, 1.f, T, T, M, C,
      (long long)T * T, 2048LL, (long long)T * C);

  // 6. reduce + normalize (grid-stride, 2048 blocks; attn -> P0 in place)
  reduce_pv2<<<2048, 256, 0, stream>>>(P0, P1, rowsum, attn);

  // 7. out = attn Wo^T + bo (f32, 256 blocks BN=128)
  gemm2ph<2><<<dim3(C / 128, M / 256, 1), 512, 0, stream>>>(
      attn, Wob, d_out, bws + 3 * C, C, C, C, C);
}

// Round 18
// 181.726 us; speedup vs baseline: 1.0753x; 1.0075x over previous
//
#include <hip/hip_runtime.h>

// Masked self-attention, B=4 T=2048 C=1024 (single head, head dim = C).
// r18 = r17 (banked 183.1 µs) with gemm8's K-loop re-staged for T4-depth:
// stages moved to earliest-legal phases (+2-tile lead into CURRENT buf:
// p1: A/B h0(t+2), p2: A h1(t+2), p3: B h1(t+2)), ONE vmcnt(8)/K-tile at p3
// (tile t+1 forced with 4-6 phases latency allowance; 8 ops = tile t+2 stay
// in flight). Consumption order, barriers (2/phase), swizzles unchanged.
//  gemm8  : 256x256 / BK=64 / 8-wave deep-staged pipelined.
//           EPI 3 = bf16+bias[col] (QK), 5 = split-K2 partial (PV),
//           6 = scores exp+rowsum (tri early-exit).
//  gemm2ph: 256x128 2-phase (Vt-proj bf16+bias[row]; out-proj f32+bias[col]).
// Pipeline: prep | QK | Vt | scores | PV splitK2 | reduce2 | out.

typedef __attribute__((ext_vector_type(8))) short short8;
typedef __attribute__((ext_vector_type(4))) float f32x4;
typedef __attribute__((ext_vector_type(4))) unsigned short us4;
typedef __attribute__((ext_vector_type(8))) unsigned short us8;
typedef __attribute__((ext_vector_type(4))) float fl4;

__device__ __forceinline__ unsigned short f2b(float f) {
  unsigned int u = __builtin_bit_cast(unsigned int, f);
  u += 0x7fffu + ((u >> 16) & 1u);   // round-to-nearest-even
  return (unsigned short)(u >> 16);
}
__device__ __forceinline__ float b2f(unsigned short h) {
  unsigned int u = ((unsigned int)h) << 16;
  return __builtin_bit_cast(float, u);
}

// ------- prep (grid-stride): converts + bias packing + rowsum zero -------
__global__ __launch_bounds__(256) void prep_kernel(
    const float* __restrict__ x,
    const float* __restrict__ Wq, const float* __restrict__ Wk,
    const float* __restrict__ Wv, const float* __restrict__ Wo,
    const float* __restrict__ bq, const float* __restrict__ bk,
    const float* __restrict__ bv, const float* __restrict__ bo,
    unsigned short* __restrict__ xb, unsigned short* __restrict__ Wqkvb,
    unsigned short* __restrict__ Wob, float* __restrict__ bws,
    float* __restrict__ rows) {
  const unsigned stride = gridDim.x * 256u;
  for (unsigned i = blockIdx.x * 256u + threadIdx.x; i < 3148800u; i += stride) {
    if (i < 2097152u) {
      fl4 f = *(const fl4*)&x[(size_t)i << 2];
      us4 o;
#pragma unroll
      for (int j = 0; j < 4; ++j) o[j] = f2b(f[j]);
      *(us4*)&xb[(size_t)i << 2] = o;
    } else if (i < 3145728u) {
      const unsigned k = i - 2097152u;
      const int w = k >> 18;
      const unsigned idx = k & 262143u;
      const float* s = w == 0 ? Wq : w == 1 ? Wk : w == 2 ? Wv : Wo;
      unsigned short* d = w < 3 ? Wqkvb + (size_t)w * 1024 * 1024 : Wob;
      fl4 f = *(const fl4*)&s[(size_t)idx << 2];
      us4 o;
#pragma unroll
      for (int j = 0; j < 4; ++j) o[j] = f2b(f[j]);
      *(us4*)&d[(size_t)idx << 2] = o;
    } else if (i < 3146752u) {
      const unsigned j = i - 3145728u;
      const int sel = j >> 8;
      const unsigned within = j & 255u;
      const float* p = sel == 0 ? bq : sel == 1 ? bk : sel == 2 ? bv : bo;
      *(fl4*)&bws[(size_t)j << 2] = *(const fl4*)&p[(size_t)within << 2];
    } else {
      const unsigned j = i - 3146752u;
      *(fl4*)&rows[(size_t)j << 2] = fl4{0.f, 0.f, 0.f, 0.f};
    }
  }
}

#define RD_A(dst, basep)                                                   \
  _Pragma("unroll") for (int mi = 0; mi < 4; ++mi)                         \
  _Pragma("unroll") for (int ks = 0; ks < 2; ++ks)                         \
      dst[mi][ks] = *(const short8*)((basep) + offA[mi][ks]);

#define RD_B(dst, basep)                                                   \
  _Pragma("unroll") for (int nj = 0; nj < 2; ++nj)                         \
  _Pragma("unroll") for (int ks = 0; ks < 2; ++ks)                         \
      dst[nj][ks] = *(const short8*)((basep) + offB[nj][ks]);

#define MFMA16(AF, BF, MI0, NJ0)                                           \
  __builtin_amdgcn_s_setprio(1);                                           \
  _Pragma("unroll") for (int ks = 0; ks < 2; ++ks)                         \
  _Pragma("unroll") for (int mi = 0; mi < 4; ++mi)                         \
  _Pragma("unroll") for (int nj = 0; nj < 2; ++nj)                         \
      acc[(MI0) + mi][(NJ0) + nj] = __builtin_amdgcn_mfma_f32_16x16x32_bf16( \
          AF[mi][ks], BF[nj][ks], acc[(MI0) + mi][(NJ0) + nj], 0, 0, 0);   \
  __builtin_amdgcn_s_setprio(0);

// Deep-staged 8-barrier K-loop (T4: +2-tile stage lead, one vmcnt(8)/tile).
// Hazard ledger: each half overwritten >=1 barrier after its last LDS read
// (fragments are register-resident); vmcnt(8) at p3 forces all of tile t+1
// (only tile t+2's 4 halves = 8 ops may remain in flight). Tail stages clamp
// to nt-1: identical bytes or dead halves (benign).
#define KLOOP_BODY                                                         \
  stA(0, 0, 0); stB(0, 0, 0); stA(0, 1, 0); stB(0, 1, 0);                  \
  stA(1, 0, 1); stB(1, 0, 1); stA(1, 1, 1); stB(1, 1, 1);                  \
  asm volatile("s_waitcnt vmcnt(8)" ::: "memory");                         \
  __builtin_amdgcn_s_barrier();                                            \
  for (int t = 0; t < nt; ++t) {                                           \
    const int buf = t & 1;                                                 \
    const char* Ab0 = (const char*)&lA[buf][0][0];                         \
    const char* Ab1 = (const char*)&lA[buf][1][0];                         \
    const char* Bb0 = (const char*)&lB[buf][0][0];                         \
    const char* Bb1 = (const char*)&lB[buf][1][0];                         \
    short8 a0[4][2], a1[4][2], b0[2][2], b1[2][2];                         \
    RD_A(a0, Ab0);                                                         \
    RD_B(b0, Bb0);                                                         \
    __builtin_amdgcn_s_barrier();                                          \
    MFMA16(a0, b0, 0, 0);                                                  \
    __builtin_amdgcn_s_barrier();                                          \
    RD_A(a1, Ab1);                                                         \
    stA(buf, 0, t + 2);                                                    \
    stB(buf, 0, t + 2);                                                    \
    __builtin_amdgcn_s_barrier();                                          \
    MFMA16(a1, b0, 4, 0);                                                  \
    __builtin_amdgcn_s_barrier();                                          \
    RD_B(b1, Bb1);                                                         \
    stA(buf, 1, t + 2);                                                    \
    __builtin_amdgcn_s_barrier();                                          \
    MFMA16(a1, b1, 4, 2);                                                  \
    __builtin_amdgcn_s_barrier();                                          \
    stB(buf, 1, t + 2);                                                    \
    asm volatile("s_waitcnt vmcnt(8)" ::: "memory");                       \
    __builtin_amdgcn_s_barrier();                                          \
    MFMA16(a0, b1, 0, 2);                                                  \
    __builtin_amdgcn_s_barrier();                                          \
  }                                                                        \
  asm volatile("s_waitcnt vmcnt(0)" ::: "memory");

// ---------------- gemm8: 256x256 deep-staged pipelined ----------------
// EPI: 3 = bf16 + bias[col]   5 = split-K2 bf16 partial (half -> P0|P1)
//      6 = scores: bf16 exp(v*scale) causal-masked + rowsum atomics
template<int EPI, bool SPLIT2, bool SKIP_UPPER>
__global__ __launch_bounds__(512, 2)
void gemm8(const unsigned short* __restrict__ A, const unsigned short* __restrict__ B,
           void* __restrict__ Cout, const float* __restrict__ bias,
           float* __restrict__ rows, float scale, int K,
           int lda, int ldb, int ldc,
           long long sAz, long long sBz, long long sCz)
{
  const int gx = gridDim.x;
  const int nwg = gx * gridDim.y;
  int flat = blockIdx.y * gx + blockIdx.x;
  { const int q = nwg >> 3, r = nwg & 7, xc = flat & 7, i = flat >> 3;
    flat = (xc < r ? xc * (q + 1) : r * (q + 1) + (xc - r) * q) + i; }
  const int m0 = (flat / gx) << 8;
  const int n0 = (flat % gx) << 8;
  if (SKIP_UPPER && n0 > m0 + 255) return;   // fully-masked score block
  const int zraw = blockIdx.z;
  const int z = SPLIT2 ? (zraw >> 1) : zraw;

  int kBeg = 0, kEnd = K;
  if (SPLIT2) {                        // balanced causal half (PV)
    const int kFull = m0 + 256;
    const int kMid = kFull >> 1;
    kBeg = (zraw & 1) ? kMid : 0;
    kEnd = (zraw & 1) ? kFull : kMid;
  }
  const int nt = (kEnd - kBeg) >> 6;

  __shared__ unsigned short lA[2][2][8192];
  __shared__ unsigned short lB[2][2][8192];

  const int tid = threadIdx.x, lane = tid & 63, wid = tid >> 6;
  const int wm = wid >> 2, wn = wid & 3;
  const int fr = lane & 15, kg = lane >> 4;

  const unsigned short* Ab = A + (size_t)z * sAz;
  const unsigned short* Bb = B + (size_t)z * sBz;

  const int xorv = (fr & 7) << 4;
  int offA[4][2], offB[2][2];
#pragma unroll
  for (int mi = 0; mi < 4; ++mi)
#pragma unroll
    for (int ks = 0; ks < 2; ++ks)
      offA[mi][ks] = ((wm << 6) + (mi << 4) + fr) * 128 + (((ks << 6) + (kg << 4)) ^ xorv);
#pragma unroll
  for (int nj = 0; nj < 2; ++nj)
#pragma unroll
    for (int ks = 0; ks < 2; ++ks)
      offB[nj][ks] = ((wn << 5) + (nj << 4) + fr) * 128 + (((ks << 6) + (kg << 4)) ^ xorv);

  const int srow = tid >> 3;
  const int scol = (((tid & 7) ^ (srow & 7)) << 3);
  const unsigned short* aS = Ab + (size_t)(m0 + srow) * lda + scol + kBeg;
  const unsigned short* bS = Bb + (size_t)(n0 + srow) * ldb + scol + kBeg;

  auto stA = [&](int buf, int h, int tt) {
    int ttc = tt < nt ? tt : nt - 1;
    const unsigned short* s0 = aS + (size_t)(h << 7) * lda + (ttc << 6);
#pragma unroll
    for (int c = 0; c < 2; ++c)
      __builtin_amdgcn_global_load_lds(
          (const __attribute__((address_space(1))) void*)(s0 + (size_t)(c << 6) * lda),
          (__attribute__((address_space(3))) void*)((char*)&lA[buf][h][0] + (c << 13) + (tid << 4)),
          16, 0, 0);
  };
  auto stB = [&](int buf, int h, int tt) {
    int ttc = tt < nt ? tt : nt - 1;
    const unsigned short* s0 = bS + (size_t)(h << 7) * ldb + (ttc << 6);
#pragma unroll
    for (int c = 0; c < 2; ++c)
      __builtin_amdgcn_global_load_lds(
          (const __attribute__((address_space(1))) void*)(s0 + (size_t)(c << 6) * ldb),
          (__attribute__((address_space(3))) void*)((char*)&lB[buf][h][0] + (c << 13) + (tid << 4)),
          16, 0, 0);
  };

  f32x4 acc[8][4];
#pragma unroll
  for (int i = 0; i < 8; ++i)
#pragma unroll
    for (int j = 0; j < 4; ++j) acc[i][j] = f32x4{0.f, 0.f, 0.f, 0.f};

  KLOOP_BODY

  if (EPI == 6) {
    unsigned short* Ch = (unsigned short*)Cout + (size_t)z * sCz;
#pragma unroll
    for (int mig = 0; mig < 8; ++mig) {
      const int row = m0 + (mig >> 2) * 128 + wm * 64 + (mig & 3) * 16 + (kg << 2);
#pragma unroll
      for (int jj = 0; jj < 4; ++jj) {
        const int r = row + jj;
        float rs = 0.f;
#pragma unroll
        for (int njg = 0; njg < 4; ++njg) {
          const int col = n0 + (njg >> 1) * 128 + wn * 32 + (njg & 1) * 16 + fr;
          const float ee = (col <= r) ? __expf(acc[mig][njg][jj] * scale) : 0.f;
          rs += ee;
          Ch[(size_t)r * ldc + col] = f2b(ee);
        }
#pragma unroll
        for (int mk = 1; mk <= 8; mk <<= 1) rs += __shfl_xor(rs, mk, 64);
        if (fr == 0) atomicAdd(&rows[z * 2048 + r], rs);
      }
    }
    return;
  }
#pragma unroll
  for (int mig = 0; mig < 8; ++mig)
#pragma unroll
    for (int njg = 0; njg < 4; ++njg) {
      const int row = m0 + (mig >> 2) * 128 + wm * 64 + (mig & 3) * 16 + (kg << 2);
      const int col = n0 + (njg >> 1) * 128 + wn * 32 + (njg & 1) * 16 + fr;
      f32x4 v = acc[mig][njg];
      if (EPI == 3) {
        unsigned short* Ch = (unsigned short*)Cout;
        const float bb = bias[col];
#pragma unroll
        for (int jj = 0; jj < 4; ++jj)
          Ch[(size_t)(row + jj) * ldc + col] = f2b(v[jj] + bb);
      } else {   // EPI == 5: split-K2 partial; half selects P0|P1
        unsigned short* Ch = (unsigned short*)Cout +
            (size_t)(zraw & 1) * 8388608 + (size_t)z * sCz;
#pragma unroll
        for (int jj = 0; jj < 4; ++jj)
          Ch[(size_t)(row + jj) * ldc + col] = f2b(v[jj]);
      }
    }
}

// ---------------- gemm2ph: 256x128 2-phase, 4-barrier (unchanged) ----------
// EPI: 2 = f32 + bias[col] (out-proj)   4 = bf16 + bias[row] (Vt-proj)
template<int EPI>
__global__ __launch_bounds__(512, 2)
void gemm2ph(const unsigned short* __restrict__ A, const unsigned short* __restrict__ B,
             void* __restrict__ Cout, const float* __restrict__ bias,
             int K, int lda, int ldb, int ldc)
{
  const int gx = gridDim.x;
  const int nwg = gx * gridDim.y;
  int flat = blockIdx.y * gx + blockIdx.x;
  { const int q = nwg >> 3, r = nwg & 7, xc = flat & 7, i = flat >> 3;
    flat = (xc < r ? xc * (q + 1) : r * (q + 1) + (xc - r) * q) + i; }
  const int m0 = (flat / gx) << 8;
  const int n0 = (flat % gx) << 7;
  const int nt = K >> 6;

  __shared__ unsigned short lA[2][2][8192];   // 64 KB
  __shared__ unsigned short lB[2][8192];      // 32 KB

  const int tid = threadIdx.x, lane = tid & 63, wid = tid >> 6;
  const int wm = wid >> 2, wn = wid & 3;
  const int fr = lane & 15, kg = lane >> 4;

  const int xorv = (fr & 7) << 4;
  int offA[4][2], offB[2][2];
#pragma unroll
  for (int mi = 0; mi < 4; ++mi)
#pragma unroll
    for (int ks = 0; ks < 2; ++ks)
      offA[mi][ks] = ((wm << 6) + (mi << 4) + fr) * 128 + (((ks << 6) + (kg << 4)) ^ xorv);
#pragma unroll
  for (int nj = 0; nj < 2; ++nj)
#pragma unroll
    for (int ks = 0; ks < 2; ++ks)
      offB[nj][ks] = ((wn << 5) + (nj << 4) + fr) * 128 + (((ks << 6) + (kg << 4)) ^ xorv);

  const int srow = tid >> 3;
  const int scol = (((tid & 7) ^ (srow & 7)) << 3);
  const unsigned short* aS = A + (size_t)(m0 + srow) * lda + scol;
  const unsigned short* bS = B + (size_t)(n0 + srow) * ldb + scol;

  auto stA = [&](int buf, int h, int tt) {
    int ttc = tt < nt ? tt : nt - 1;
    const unsigned short* s0 = aS + (size_t)(h << 7) * lda + (ttc << 6);
#pragma unroll
    for (int c = 0; c < 2; ++c)
      __builtin_amdgcn_global_load_lds(
          (const __attribute__((address_space(1))) void*)(s0 + (size_t)(c << 6) * lda),
          (__attribute__((address_space(3))) void*)((char*)&lA[buf][h][0] + (c << 13) + (tid << 4)),
          16, 0, 0);
  };
  auto stB = [&](int buf, int tt) {
    int ttc = tt < nt ? tt : nt - 1;
    const unsigned short* s0 = bS + (ttc << 6);
#pragma unroll
    for (int c = 0; c < 2; ++c)
      __builtin_amdgcn_global_load_lds(
          (const __attribute__((address_space(1))) void*)(s0 + (size_t)(c << 6) * ldb),
          (__attribute__((address_space(3))) void*)((char*)&lB[buf][0] + (c << 13) + (tid << 4)),
          16, 0, 0);
  };

  f32x4 acc[8][2];
#pragma unroll
  for (int i = 0; i < 8; ++i)
#pragma unroll
    for (int j = 0; j < 2; ++j) acc[i][j] = f32x4{0.f, 0.f, 0.f, 0.f};

  stB(0, 0); stA(0, 0, 0); stA(0, 1, 0);
  asm volatile("s_waitcnt vmcnt(2)" ::: "memory");
  __builtin_amdgcn_s_barrier();

  for (int t = 0; t < nt; ++t) {
    const int buf = t & 1, nbuf = buf ^ 1;
    const char* Ab0 = (const char*)&lA[buf][0][0];
    const char* Ab1 = (const char*)&lA[buf][1][0];
    const char* Bbp = (const char*)&lB[buf][0];

    short8 a0[4][2], a1[4][2], b0[2][2];

    RD_A(a0, Ab0);
    RD_B(b0, Bbp);
    stB(nbuf, t + 1); stA(nbuf, 0, t + 1);
    asm volatile("s_waitcnt vmcnt(4)" ::: "memory");
    __builtin_amdgcn_s_barrier();
    MFMA16(a0, b0, 0, 0);
    __builtin_amdgcn_s_barrier();

    RD_A(a1, Ab1);
    stA(nbuf, 1, t + 1);
    asm volatile("s_waitcnt vmcnt(2)" ::: "memory");
    __builtin_amdgcn_s_barrier();
    MFMA16(a1, b0, 4, 0);
    __builtin_amdgcn_s_barrier();
  }
  asm volatile("s_waitcnt vmcnt(0)" ::: "memory");

#pragma unroll
  for (int mig = 0; mig < 8; ++mig)
#pragma unroll
    for (int njg = 0; njg < 2; ++njg) {
      const int row = m0 + (mig >> 2) * 128 + wm * 64 + (mig & 3) * 16 + (kg << 2);
      const int col = n0 + wn * 32 + njg * 16 + fr;
      f32x4 v = acc[mig][njg];
      if (EPI == 2) {
        float* Cf = (float*)Cout;
        const float bb = bias[col];
#pragma unroll
        for (int jj = 0; jj < 4; ++jj)
          Cf[(size_t)(row + jj) * ldc + col] = v[jj] + bb;
      } else {   // EPI == 4: bias by row (Vt-proj)
        unsigned short* Ch = (unsigned short*)Cout;
#pragma unroll
        for (int jj = 0; jj < 4; ++jj)
          Ch[(size_t)(row + jj) * ldc + col] = f2b(v[jj] + bias[row + jj]);
      }
    }
}

// ---- split-K2 reduce + normalize (grid-stride): attn = (P0+P1)/rowsum ----
__global__ __launch_bounds__(256)
void reduce_pv2(const unsigned short* __restrict__ p0,
                const unsigned short* __restrict__ p1,
                const float* __restrict__ rows,
                unsigned short* __restrict__ out) {
  const unsigned stride = gridDim.x * 256u;
  for (unsigned g = blockIdx.x * 256u + threadIdx.x; g < 1048576u; g += stride) {
    const size_t i = (size_t)g << 3;
    const float inv = 1.f / rows[i >> 10];
    us8 a = *(const us8*)&p0[i];
    us8 b = *(const us8*)&p1[i];
    us8 o;
#pragma unroll
    for (int j = 0; j < 8; ++j)
      o[j] = f2b((b2f(a[j]) + b2f(b[j])) * inv);
    *(us8*)&out[i] = o;
  }
}

// ---------------- host-side launch ----------------
extern "C" void kernel_launch(void* const* d_in, const int* in_sizes, int n_in,
                              void* d_out, int out_size, void* d_ws, size_t ws_size,
                              hipStream_t stream) {
  (void)in_sizes; (void)n_in; (void)out_size; (void)ws_size;
  const float* x  = (const float*)d_in[0];
  const float* Wq = (const float*)d_in[1];
  const float* bq = (const float*)d_in[2];
  const float* Wk = (const float*)d_in[3];
  const float* bk = (const float*)d_in[4];
  const float* Wv = (const float*)d_in[5];
  const float* bv = (const float*)d_in[6];
  const float* Wo = (const float*)d_in[7];
  const float* bo = (const float*)d_in[8];

  const int B = 4, T = 2048, C = 1024;
  const int M = B * T;                                   // 8192

  unsigned short* xb    = (unsigned short*)d_ws;         // M*C
  unsigned short* Wqkvb = xb    + (size_t)M * C;         // [Wq|Wk|Wv]
  unsigned short* Wob   = Wqkvb + (size_t)3 * C * C;
  unsigned short* QK    = Wob   + (size_t)C * C;         // M*2C [Q|K]; later P0|P1
  unsigned short* Vt    = QK    + (size_t)M * 2 * C;     // [1024][8192]
  unsigned short* S     = Vt    + (size_t)M * C;         // B*T*T e-values
  float*          bws   = (float*)(S + (size_t)B * T * T);
  float*          rowsum= bws + 4096;                    // 8192 f32
  unsigned short* P0    = QK;
  unsigned short* P1    = QK + (size_t)M * C;
  unsigned short* attn  = P0;

  // 1. prep (grid-stride, 2048 blocks)
  prep_kernel<<<2048, 256, 0, stream>>>(x, Wq, Wk, Wv, Wo, bq, bk, bv, bo,
                                        xb, Wqkvb, Wob, bws, rowsum);

  // 2. QK projection (256 blocks)
  gemm8<3, false, false><<<dim3(2 * C / 256, M / 256, 1), 512, 0, stream>>>(
      xb, Wqkvb, QK, bws, nullptr, 1.f, C, C, C, 2 * C, 0LL, 0LL, 0LL);

  // 3. Vt = Wv @ x^T + bv[row] (256 blocks, BN=128)
  gemm2ph<4><<<dim3(M / 128, C / 256, 1), 512, 0, stream>>>(
      Wqkvb + (size_t)2 * C * C, xb, Vt, bws + 2 * C, C, C, C, M);

  // 4. scores: S = exp(Q K^T / 32) causal-masked + rowsum atomics
  gemm8<6, false, true><<<dim3(T / 256, T / 256, B), 512, 0, stream>>>(
      QK, QK + C, S, nullptr, rowsum, 0.03125f, C, 2 * C, 2 * C, T,
      (long long)T * 2 * C, (long long)T * 2 * C, (long long)T * T);

  // 5. PV split-K2: partials P0|P1 (z = batch*2 + half), 256 blocks
  gemm8<5, true, false><<<dim3(C / 256, T / 256, 2 * B), 512, 0, stream>>>(
      S, Vt, P0, nullptr, nullptr, 1.f, T, T, M, C,
      (long long)T * T, 2048LL, (long long)T * C);

  // 6. reduce + normalize (grid-stride, 2048 blocks; attn -> P0 in place)
  reduce_pv2<<<2048, 256, 0, stream>>>(P0, P1, rowsum, attn);

  // 7. out = attn Wo^T + bo (f32, 256 blocks BN=128)
  gemm2ph<2><<<dim3(C / 128, M / 256, 1), 512, 0, stream>>>(
      attn, Wob, d_out, bws + 3 * C, C, C, C, C);
}

// Round 19
// 181.411 us; speedup vs baseline: 1.0772x; 1.0017x over previous
//
#include <hip/hip_runtime.h>

// Masked self-attention, B=4 T=2048 C=1024 (single head, head dim = C).
// FINAL BANKED CONFIGURATION (round 18, measured best: 181.7 µs).
//  gemm8  : 256x256 / BK=64 / 8-wave deep-staged pipelined (+2-tile stage
//           lead into current buf, one vmcnt(8)/K-tile, 2 barriers/phase).
//           EPI 3 = bf16+bias[col] (QK), 5 = split-K2 partial (PV),
//           6 = scores exp+rowsum (tri early-exit).
//  gemm2ph: 256x128 2-phase (Vt-proj bf16+bias[row]; out-proj f32+bias[col]).
// LDS swizzle: 16B-slot ^= (row&7), both-sides. T1 XCD-bijective swizzle.
// Softmax fused in scores epilogue; reduce_pv2 divides by rowsum.
// prep/reduce: 2048-block grid-stride.
// Pipeline: prep | QK | Vt | scores | PV splitK2 | reduce2 | out.

typedef __attribute__((ext_vector_type(8))) short short8;
typedef __attribute__((ext_vector_type(4))) float f32x4;
typedef __attribute__((ext_vector_type(4))) unsigned short us4;
typedef __attribute__((ext_vector_type(8))) unsigned short us8;
typedef __attribute__((ext_vector_type(4))) float fl4;

__device__ __forceinline__ unsigned short f2b(float f) {
  unsigned int u = __builtin_bit_cast(unsigned int, f);
  u += 0x7fffu + ((u >> 16) & 1u);   // round-to-nearest-even
  return (unsigned short)(u >> 16);
}
__device__ __forceinline__ float b2f(unsigned short h) {
  unsigned int u = ((unsigned int)h) << 16;
  return __builtin_bit_cast(float, u);
}

// ------- prep (grid-stride): converts + bias packing + rowsum zero -------
__global__ __launch_bounds__(256) void prep_kernel(
    const float* __restrict__ x,
    const float* __restrict__ Wq, const float* __restrict__ Wk,
    const float* __restrict__ Wv, const float* __restrict__ Wo,
    const float* __restrict__ bq, const float* __restrict__ bk,
    const float* __restrict__ bv, const float* __restrict__ bo,
    unsigned short* __restrict__ xb, unsigned short* __restrict__ Wqkvb,
    unsigned short* __restrict__ Wob, float* __restrict__ bws,
    float* __restrict__ rows) {
  const unsigned stride = gridDim.x * 256u;
  for (unsigned i = blockIdx.x * 256u + threadIdx.x; i < 3148800u; i += stride) {
    if (i < 2097152u) {
      fl4 f = *(const fl4*)&x[(size_t)i << 2];
      us4 o;
#pragma unroll
      for (int j = 0; j < 4; ++j) o[j] = f2b(f[j]);
      *(us4*)&xb[(size_t)i << 2] = o;
    } else if (i < 3145728u) {
      const unsigned k = i - 2097152u;
      const int w = k >> 18;
      const unsigned idx = k & 262143u;
      const float* s = w == 0 ? Wq : w == 1 ? Wk : w == 2 ? Wv : Wo;
      unsigned short* d = w < 3 ? Wqkvb + (size_t)w * 1024 * 1024 : Wob;
      fl4 f = *(const fl4*)&s[(size_t)idx << 2];
      us4 o;
#pragma unroll
      for (int j = 0; j < 4; ++j) o[j] = f2b(f[j]);
      *(us4*)&d[(size_t)idx << 2] = o;
    } else if (i < 3146752u) {
      const unsigned j = i - 3145728u;
      const int sel = j >> 8;
      const unsigned within = j & 255u;
      const float* p = sel == 0 ? bq : sel == 1 ? bk : sel == 2 ? bv : bo;
      *(fl4*)&bws[(size_t)j << 2] = *(const fl4*)&p[(size_t)within << 2];
    } else {
      const unsigned j = i - 3146752u;
      *(fl4*)&rows[(size_t)j << 2] = fl4{0.f, 0.f, 0.f, 0.f};
    }
  }
}

#define RD_A(dst, basep)                                                   \
  _Pragma("unroll") for (int mi = 0; mi < 4; ++mi)                         \
  _Pragma("unroll") for (int ks = 0; ks < 2; ++ks)                         \
      dst[mi][ks] = *(const short8*)((basep) + offA[mi][ks]);

#define RD_B(dst, basep)                                                   \
  _Pragma("unroll") for (int nj = 0; nj < 2; ++nj)                         \
  _Pragma("unroll") for (int ks = 0; ks < 2; ++ks)                         \
      dst[nj][ks] = *(const short8*)((basep) + offB[nj][ks]);

#define MFMA16(AF, BF, MI0, NJ0)                                           \
  __builtin_amdgcn_s_setprio(1);                                           \
  _Pragma("unroll") for (int ks = 0; ks < 2; ++ks)                         \
  _Pragma("unroll") for (int mi = 0; mi < 4; ++mi)                         \
  _Pragma("unroll") for (int nj = 0; nj < 2; ++nj)                         \
      acc[(MI0) + mi][(NJ0) + nj] = __builtin_amdgcn_mfma_f32_16x16x32_bf16( \
          AF[mi][ks], BF[nj][ks], acc[(MI0) + mi][(NJ0) + nj], 0, 0, 0);   \
  __builtin_amdgcn_s_setprio(0);

// Deep-staged 8-barrier K-loop (T4: +2-tile stage lead, one vmcnt(8)/tile).
#define KLOOP_BODY                                                         \
  stA(0, 0, 0); stB(0, 0, 0); stA(0, 1, 0); stB(0, 1, 0);                  \
  stA(1, 0, 1); stB(1, 0, 1); stA(1, 1, 1); stB(1, 1, 1);                  \
  asm volatile("s_waitcnt vmcnt(8)" ::: "memory");                         \
  __builtin_amdgcn_s_barrier();                                            \
  for (int t = 0; t < nt; ++t) {                                           \
    const int buf = t & 1;                                                 \
    const char* Ab0 = (const char*)&lA[buf][0][0];                         \
    const char* Ab1 = (const char*)&lA[buf][1][0];                         \
    const char* Bb0 = (const char*)&lB[buf][0][0];                         \
    const char* Bb1 = (const char*)&lB[buf][1][0];                         \
    short8 a0[4][2], a1[4][2], b0[2][2], b1[2][2];                         \
    RD_A(a0, Ab0);                                                         \
    RD_B(b0, Bb0);                                                         \
    __builtin_amdgcn_s_barrier();                                          \
    MFMA16(a0, b0, 0, 0);                                                  \
    __builtin_amdgcn_s_barrier();                                          \
    RD_A(a1, Ab1);                                                         \
    stA(buf, 0, t + 2);                                                    \
    stB(buf, 0, t + 2);                                                    \
    __builtin_amdgcn_s_barrier();                                          \
    MFMA16(a1, b0, 4, 0);                                                  \
    __builtin_amdgcn_s_barrier();                                          \
    RD_B(b1, Bb1);                                                         \
    stA(buf, 1, t + 2);                                                    \
    __builtin_amdgcn_s_barrier();                                          \
    MFMA16(a1, b1, 4, 2);                                                  \
    __builtin_amdgcn_s_barrier();                                          \
    stB(buf, 1, t + 2);                                                    \
    asm volatile("s_waitcnt vmcnt(8)" ::: "memory");                       \
    __builtin_amdgcn_s_barrier();                                          \
    MFMA16(a0, b1, 0, 2);                                                  \
    __builtin_amdgcn_s_barrier();                                          \
  }                                                                        \
  asm volatile("s_waitcnt vmcnt(0)" ::: "memory");

// ---------------- gemm8: 256x256 deep-staged pipelined ----------------
// EPI: 3 = bf16 + bias[col]   5 = split-K2 bf16 partial (half -> P0|P1)
//      6 = scores: bf16 exp(v*scale) causal-masked + rowsum atomics
template<int EPI, bool SPLIT2, bool SKIP_UPPER>
__global__ __launch_bounds__(512, 2)
void gemm8(const unsigned short* __restrict__ A, const unsigned short* __restrict__ B,
           void* __restrict__ Cout, const float* __restrict__ bias,
           float* __restrict__ rows, float scale, int K,
           int lda, int ldb, int ldc,
           long long sAz, long long sBz, long long sCz)
{
  const int gx = gridDim.x;
  const int nwg = gx * gridDim.y;
  int flat = blockIdx.y * gx + blockIdx.x;
  { const int q = nwg >> 3, r = nwg & 7, xc = flat & 7, i = flat >> 3;
    flat = (xc < r ? xc * (q + 1) : r * (q + 1) + (xc - r) * q) + i; }
  const int m0 = (flat / gx) << 8;
  const int n0 = (flat % gx) << 8;
  if (SKIP_UPPER && n0 > m0 + 255) return;   // fully-masked score block
  const int zraw = blockIdx.z;
  const int z = SPLIT2 ? (zraw >> 1) : zraw;

  int kBeg = 0, kEnd = K;
  if (SPLIT2) {                        // balanced causal half (PV)
    const int kFull = m0 + 256;
    const int kMid = kFull >> 1;
    kBeg = (zraw & 1) ? kMid : 0;
    kEnd = (zraw & 1) ? kFull : kMid;
  }
  const int nt = (kEnd - kBeg) >> 6;

  __shared__ unsigned short lA[2][2][8192];
  __shared__ unsigned short lB[2][2][8192];

  const int tid = threadIdx.x, lane = tid & 63, wid = tid >> 6;
  const int wm = wid >> 2, wn = wid & 3;
  const int fr = lane & 15, kg = lane >> 4;

  const unsigned short* Ab = A + (size_t)z * sAz;
  const unsigned short* Bb = B + (size_t)z * sBz;

  const int xorv = (fr & 7) << 4;
  int offA[4][2], offB[2][2];
#pragma unroll
  for (int mi = 0; mi < 4; ++mi)
#pragma unroll
    for (int ks = 0; ks < 2; ++ks)
      offA[mi][ks] = ((wm << 6) + (mi << 4) + fr) * 128 + (((ks << 6) + (kg << 4)) ^ xorv);
#pragma unroll
  for (int nj = 0; nj < 2; ++nj)
#pragma unroll
    for (int ks = 0; ks < 2; ++ks)
      offB[nj][ks] = ((wn << 5) + (nj << 4) + fr) * 128 + (((ks << 6) + (kg << 4)) ^ xorv);

  const int srow = tid >> 3;
  const int scol = (((tid & 7) ^ (srow & 7)) << 3);
  const unsigned short* aS = Ab + (size_t)(m0 + srow) * lda + scol + kBeg;
  const unsigned short* bS = Bb + (size_t)(n0 + srow) * ldb + scol + kBeg;

  auto stA = [&](int buf, int h, int tt) {
    int ttc = tt < nt ? tt : nt - 1;
    const unsigned short* s0 = aS + (size_t)(h << 7) * lda + (ttc << 6);
#pragma unroll
    for (int c = 0; c < 2; ++c)
      __builtin_amdgcn_global_load_lds(
          (const __attribute__((address_space(1))) void*)(s0 + (size_t)(c << 6) * lda),
          (__attribute__((address_space(3))) void*)((char*)&lA[buf][h][0] + (c << 13) + (tid << 4)),
          16, 0, 0);
  };
  auto stB = [&](int buf, int h, int tt) {
    int ttc = tt < nt ? tt : nt - 1;
    const unsigned short* s0 = bS + (size_t)(h << 7) * ldb + (ttc << 6);
#pragma unroll
    for (int c = 0; c < 2; ++c)
      __builtin_amdgcn_global_load_lds(
          (const __attribute__((address_space(1))) void*)(s0 + (size_t)(c << 6) * ldb),
          (__attribute__((address_space(3))) void*)((char*)&lB[buf][h][0] + (c << 13) + (tid << 4)),
          16, 0, 0);
  };

  f32x4 acc[8][4];
#pragma unroll
  for (int i = 0; i < 8; ++i)
#pragma unroll
    for (int j = 0; j < 4; ++j) acc[i][j] = f32x4{0.f, 0.f, 0.f, 0.f};

  KLOOP_BODY

  if (EPI == 6) {
    unsigned short* Ch = (unsigned short*)Cout + (size_t)z * sCz;
#pragma unroll
    for (int mig = 0; mig < 8; ++mig) {
      const int row = m0 + (mig >> 2) * 128 + wm * 64 + (mig & 3) * 16 + (kg << 2);
#pragma unroll
      for (int jj = 0; jj < 4; ++jj) {
        const int r = row + jj;
        float rs = 0.f;
#pragma unroll
        for (int njg = 0; njg < 4; ++njg) {
          const int col = n0 + (njg >> 1) * 128 + wn * 32 + (njg & 1) * 16 + fr;
          const float ee = (col <= r) ? __expf(acc[mig][njg][jj] * scale) : 0.f;
          rs += ee;
          Ch[(size_t)r * ldc + col] = f2b(ee);
        }
#pragma unroll
        for (int mk = 1; mk <= 8; mk <<= 1) rs += __shfl_xor(rs, mk, 64);
        if (fr == 0) atomicAdd(&rows[z * 2048 + r], rs);
      }
    }
    return;
  }
#pragma unroll
  for (int mig = 0; mig < 8; ++mig)
#pragma unroll
    for (int njg = 0; njg < 4; ++njg) {
      const int row = m0 + (mig >> 2) * 128 + wm * 64 + (mig & 3) * 16 + (kg << 2);
      const int col = n0 + (njg >> 1) * 128 + wn * 32 + (njg & 1) * 16 + fr;
      f32x4 v = acc[mig][njg];
      if (EPI == 3) {
        unsigned short* Ch = (unsigned short*)Cout;
        const float bb = bias[col];
#pragma unroll
        for (int jj = 0; jj < 4; ++jj)
          Ch[(size_t)(row + jj) * ldc + col] = f2b(v[jj] + bb);
      } else {   // EPI == 5: split-K2 partial; half selects P0|P1
        unsigned short* Ch = (unsigned short*)Cout +
            (size_t)(zraw & 1) * 8388608 + (size_t)z * sCz;
#pragma unroll
        for (int jj = 0; jj < 4; ++jj)
          Ch[(size_t)(row + jj) * ldc + col] = f2b(v[jj]);
      }
    }
}

// ---------------- gemm2ph: 256x128 2-phase, 4-barrier ----------------
// EPI: 2 = f32 + bias[col] (out-proj)   4 = bf16 + bias[row] (Vt-proj)
template<int EPI>
__global__ __launch_bounds__(512, 2)
void gemm2ph(const unsigned short* __restrict__ A, const unsigned short* __restrict__ B,
             void* __restrict__ Cout, const float* __restrict__ bias,
             int K, int lda, int ldb, int ldc)
{
  const int gx = gridDim.x;
  const int nwg = gx * gridDim.y;
  int flat = blockIdx.y * gx + blockIdx.x;
  { const int q = nwg >> 3, r = nwg & 7, xc = flat & 7, i = flat >> 3;
    flat = (xc < r ? xc * (q + 1) : r * (q + 1) + (xc - r) * q) + i; }
  const int m0 = (flat / gx) << 8;
  const int n0 = (flat % gx) << 7;
  const int nt = K >> 6;

  __shared__ unsigned short lA[2][2][8192];   // 64 KB
  __shared__ unsigned short lB[2][8192];      // 32 KB

  const int tid = threadIdx.x, lane = tid & 63, wid = tid >> 6;
  const int wm = wid >> 2, wn = wid & 3;
  const int fr = lane & 15, kg = lane >> 4;

  const int xorv = (fr & 7) << 4;
  int offA[4][2], offB[2][2];
#pragma unroll
  for (int mi = 0; mi < 4; ++mi)
#pragma unroll
    for (int ks = 0; ks < 2; ++ks)
      offA[mi][ks] = ((wm << 6) + (mi << 4) + fr) * 128 + (((ks << 6) + (kg << 4)) ^ xorv);
#pragma unroll
  for (int nj = 0; nj < 2; ++nj)
#pragma unroll
    for (int ks = 0; ks < 2; ++ks)
      offB[nj][ks] = ((wn << 5) + (nj << 4) + fr) * 128 + (((ks << 6) + (kg << 4)) ^ xorv);

  const int srow = tid >> 3;
  const int scol = (((tid & 7) ^ (srow & 7)) << 3);
  const unsigned short* aS = A + (size_t)(m0 + srow) * lda + scol;
  const unsigned short* bS = B + (size_t)(n0 + srow) * ldb + scol;

  auto stA = [&](int buf, int h, int tt) {
    int ttc = tt < nt ? tt : nt - 1;
    const unsigned short* s0 = aS + (size_t)(h << 7) * lda + (ttc << 6);
#pragma unroll
    for (int c = 0; c < 2; ++c)
      __builtin_amdgcn_global_load_lds(
          (const __attribute__((address_space(1))) void*)(s0 + (size_t)(c << 6) * lda),
          (__attribute__((address_space(3))) void*)((char*)&lA[buf][h][0] + (c << 13) + (tid << 4)),
          16, 0, 0);
  };
  auto stB = [&](int buf, int tt) {
    int ttc = tt < nt ? tt : nt - 1;
    const unsigned short* s0 = bS + (ttc << 6);
#pragma unroll
    for (int c = 0; c < 2; ++c)
      __builtin_amdgcn_global_load_lds(
          (const __attribute__((address_space(1))) void*)(s0 + (size_t)(c << 6) * ldb),
          (__attribute__((address_space(3))) void*)((char*)&lB[buf][0] + (c << 13) + (tid << 4)),
          16, 0, 0);
  };

  f32x4 acc[8][2];
#pragma unroll
  for (int i = 0; i < 8; ++i)
#pragma unroll
    for (int j = 0; j < 2; ++j) acc[i][j] = f32x4{0.f, 0.f, 0.f, 0.f};

  stB(0, 0); stA(0, 0, 0); stA(0, 1, 0);
  asm volatile("s_waitcnt vmcnt(2)" ::: "memory");
  __builtin_amdgcn_s_barrier();

  for (int t = 0; t < nt; ++t) {
    const int buf = t & 1, nbuf = buf ^ 1;
    const char* Ab0 = (const char*)&lA[buf][0][0];
    const char* Ab1 = (const char*)&lA[buf][1][0];
    const char* Bbp = (const char*)&lB[buf][0];

    short8 a0[4][2], a1[4][2], b0[2][2];

    RD_A(a0, Ab0);
    RD_B(b0, Bbp);
    stB(nbuf, t + 1); stA(nbuf, 0, t + 1);
    asm volatile("s_waitcnt vmcnt(4)" ::: "memory");
    __builtin_amdgcn_s_barrier();
    MFMA16(a0, b0, 0, 0);
    __builtin_amdgcn_s_barrier();

    RD_A(a1, Ab1);
    stA(nbuf, 1, t + 1);
    asm volatile("s_waitcnt vmcnt(2)" ::: "memory");
    __builtin_amdgcn_s_barrier();
    MFMA16(a1, b0, 4, 0);
    __builtin_amdgcn_s_barrier();
  }
  asm volatile("s_waitcnt vmcnt(0)" ::: "memory");

#pragma unroll
  for (int mig = 0; mig < 8; ++mig)
#pragma unroll
    for (int njg = 0; njg < 2; ++njg) {
      const int row = m0 + (mig >> 2) * 128 + wm * 64 + (mig & 3) * 16 + (kg << 2);
      const int col = n0 + wn * 32 + njg * 16 + fr;
      f32x4 v = acc[mig][njg];
      if (EPI == 2) {
        float* Cf = (float*)Cout;
        const float bb = bias[col];
#pragma unroll
        for (int jj = 0; jj < 4; ++jj)
          Cf[(size_t)(row + jj) * ldc + col] = v[jj] + bb;
      } else {   // EPI == 4: bias by row (Vt-proj)
        unsigned short* Ch = (unsigned short*)Cout;
#pragma unroll
        for (int jj = 0; jj < 4; ++jj)
          Ch[(size_t)(row + jj) * ldc + col] = f2b(v[jj] + bias[row + jj]);
      }
    }
}

// ---- split-K2 reduce + normalize (grid-stride): attn = (P0+P1)/rowsum ----
__global__ __launch_bounds__(256)
void reduce_pv2(const unsigned short* __restrict__ p0,
                const unsigned short* __restrict__ p1,
                const float* __restrict__ rows,
                unsigned short* __restrict__ out) {
  const unsigned stride = gridDim.x * 256u;
  for (unsigned g = blockIdx.x * 256u + threadIdx.x; g < 1048576u; g += stride) {
    const size_t i = (size_t)g << 3;
    const float inv = 1.f / rows[i >> 10];
    us8 a = *(const us8*)&p0[i];
    us8 b = *(const us8*)&p1[i];
    us8 o;
#pragma unroll
    for (int j = 0; j < 8; ++j)
      o[j] = f2b((b2f(a[j]) + b2f(b[j])) * inv);
    *(us8*)&out[i] = o;
  }
}

// ---------------- host-side launch ----------------
extern "C" void kernel_launch(void* const* d_in, const int* in_sizes, int n_in,
                              void* d_out, int out_size, void* d_ws, size_t ws_size,
                              hipStream_t stream) {
  (void)in_sizes; (void)n_in; (void)out_size; (void)ws_size;
  const float* x  = (const float*)d_in[0];
  const float* Wq = (const float*)d_in[1];
  const float* bq = (const float*)d_in[2];
  const float* Wk = (const float*)d_in[3];
  const float* bk = (const float*)d_in[4];
  const float* Wv = (const float*)d_in[5];
  const float* bv = (const float*)d_in[6];
  const float* Wo = (const float*)d_in[7];
  const float* bo = (const float*)d_in[8];

  const int B = 4, T = 2048, C = 1024;
  const int M = B * T;                                   // 8192

  unsigned short* xb    = (unsigned short*)d_ws;         // M*C
  unsigned short* Wqkvb = xb    + (size_t)M * C;         // [Wq|Wk|Wv]
  unsigned short* Wob   = Wqkvb + (size_t)3 * C * C;
  unsigned short* QK    = Wob   + (size_t)C * C;         // M*2C [Q|K]; later P0|P1
  unsigned short* Vt    = QK    + (size_t)M * 2 * C;     // [1024][8192]
  unsigned short* S     = Vt    + (size_t)M * C;         // B*T*T e-values
  float*          bws   = (float*)(S + (size_t)B * T * T);
  float*          rowsum= bws + 4096;                    // 8192 f32
  unsigned short* P0    = QK;
  unsigned short* P1    = QK + (size_t)M * C;
  unsigned short* attn  = P0;

  // 1. prep (grid-stride, 2048 blocks)
  prep_kernel<<<2048, 256, 0, stream>>>(x, Wq, Wk, Wv, Wo, bq, bk, bv, bo,
                                        xb, Wqkvb, Wob, bws, rowsum);

  // 2. QK projection (256 blocks)
  gemm8<3, false, false><<<dim3(2 * C / 256, M / 256, 1), 512, 0, stream>>>(
      xb, Wqkvb, QK, bws, nullptr, 1.f, C, C, C, 2 * C, 0LL, 0LL, 0LL);

  // 3. Vt = Wv @ x^T + bv[row] (256 blocks, BN=128)
  gemm2ph<4><<<dim3(M / 128, C / 256, 1), 512, 0, stream>>>(
      Wqkvb + (size_t)2 * C * C, xb, Vt, bws + 2 * C, C, C, C, M);

  // 4. scores: S = exp(Q K^T / 32) causal-masked + rowsum atomics
  gemm8<6, false, true><<<dim3(T / 256, T / 256, B), 512, 0, stream>>>(
      QK, QK + C, S, nullptr, rowsum, 0.03125f, C, 2 * C, 2 * C, T,
      (long long)T * 2 * C, (long long)T * 2 * C, (long long)T * T);

  // 5. PV split-K2: partials P0|P1 (z = batch*2 + half), 256 blocks
  gemm8<5, true, false><<<dim3(C / 256, T / 256, 2 * B), 512, 0, stream>>>(
      S, Vt, P0, nullptr, nullptr, 1.f, T, T, M, C,
      (long long)T * T, 2048LL, (long long)T * C);

  // 6. reduce + normalize (grid-stride, 2048 blocks; attn -> P0 in place)
  reduce_pv2<<<2048, 256, 0, stream>>>(P0, P1, rowsum, attn);

  // 7. out = attn Wo^T + bo (f32, 256 blocks BN=128)
  gemm2ph<2><<<dim3(C / 128, M / 256, 1), 512, 0, stream>>>(
      attn, Wob, d_out, bws + 3 * C, C, C, C, C);
}